// Round 1
// baseline (331.958 us; speedup 1.0000x reference)
//
#include <hip/hip_runtime.h>
#include <hip/hip_bf16.h>
#include <stdint.h>

#define DEV __device__ __forceinline__

typedef __attribute__((ext_vector_type(8))) short bf16x8;
typedef __attribute__((ext_vector_type(4))) float f32x4;

DEV unsigned short f2bf(float f) {
  unsigned u = __builtin_bit_cast(unsigned, f);
  unsigned r = u + 0x7FFF + ((u >> 16) & 1);   // RNE
  return (unsigned short)(r >> 16);
}

typedef __attribute__((address_space(1))) void gvoid;
typedef __attribute__((address_space(3))) void lvoid;

DEV void g2l16(const void* g, void* l) {
  __builtin_amdgcn_global_load_lds((gvoid*)g, (lvoid*)l, 16, 0, 0);
}

// ---------------- fp32 -> bf16 convert ----------------
__global__ void k_cvt(const float* __restrict__ in, unsigned short* __restrict__ out, int n4) {
  int i = blockIdx.x * blockDim.x + threadIdx.x;
  int stride = gridDim.x * blockDim.x;
  for (; i < n4; i += stride) {
    float4 v = reinterpret_cast<const float4*>(in)[i];
    ushort4 o;
    o.x = f2bf(v.x); o.y = f2bf(v.y); o.z = f2bf(v.z); o.w = f2bf(v.w);
    reinterpret_cast<ushort4*>(out)[i] = o;
  }
}

// ---------------- 128x128 tile bf16 GEMM, B given as B^T [N][K], +bias ----------------
template<bool BF16OUT>
__global__ __launch_bounds__(256, 2) void k_gemm(
    const unsigned short* __restrict__ A, const unsigned short* __restrict__ B,
    const float* __restrict__ bias, void* __restrict__ C,
    int M, int N, int K) {
  __shared__ unsigned short As[128 * 32];
  __shared__ unsigned short Bs[128 * 32];
  int tid = threadIdx.x;
  int lane = tid & 63, wid = tid >> 6;
  int bm = blockIdx.y * 128, bn = blockIdx.x * 128;
  int wm = (wid >> 1) * 64, wn = (wid & 1) * 64;
  int row16 = lane & 15, kq = lane >> 4;
  f32x4 acc[4][4] = {};
  int r = tid >> 2, c = (tid & 3) * 8;
  const unsigned short* Ag = A + (size_t)(bm + r) * K + c;
  const unsigned short* Bg = B + (size_t)(bn + r) * K + c;
  for (int k0 = 0; k0 < K; k0 += 32) {
    g2l16(Ag + k0, &As[tid * 8]);
    g2l16(Ag + (size_t)64 * K + k0, &As[2048 + tid * 8]);
    g2l16(Bg + k0, &Bs[tid * 8]);
    g2l16(Bg + (size_t)64 * K + k0, &Bs[2048 + tid * 8]);
    __syncthreads();
    bf16x8 a[4], b[4];
#pragma unroll
    for (int m = 0; m < 4; m++) a[m] = *(const bf16x8*)&As[(wm + m * 16 + row16) * 32 + kq * 8];
#pragma unroll
    for (int n = 0; n < 4; n++) b[n] = *(const bf16x8*)&Bs[(wn + n * 16 + row16) * 32 + kq * 8];
#pragma unroll
    for (int m = 0; m < 4; m++)
#pragma unroll
      for (int n = 0; n < 4; n++)
        acc[m][n] = __builtin_amdgcn_mfma_f32_16x16x32_bf16(a[m], b[n], acc[m][n], 0, 0, 0);
    __syncthreads();
  }
#pragma unroll
  for (int n = 0; n < 4; n++) {
    int col = bn + wn + n * 16 + row16;
    float bv = bias[col];
#pragma unroll
    for (int m = 0; m < 4; m++) {
      int rw = bm + wm + m * 16 + kq * 4;
#pragma unroll
      for (int j = 0; j < 4; j++) {
        float v = acc[m][n][j] + bv;
        if (BF16OUT) ((unsigned short*)C)[(size_t)(rw + j) * N + col] = f2bf(v);
        else         ((float*)C)[(size_t)(rw + j) * N + col] = v;
      }
    }
  }
}

// ---------------- V transpose: packed[b,t,2560+kv*128+d] -> vT[(b*4+kv)*128+d][t] ----------------
__global__ void k_vt(const unsigned short* __restrict__ packed, unsigned short* __restrict__ vT) {
  __shared__ unsigned short tile[64][136];
  int g = blockIdx.y;            // b*4+kv
  int b = g >> 2, kv = g & 3;
  int t0 = blockIdx.x * 64;
  int tid = threadIdx.x;
#pragma unroll
  for (int i = 0; i < 4; i++) {
    int tl = i * 16 + (tid >> 4);
    int d0 = (tid & 15) * 8;
    bf16x8 v = *(const bf16x8*)&packed[(size_t)(b * 2048 + t0 + tl) * 3072 + 2560 + kv * 128 + d0];
    *(bf16x8*)&tile[tl][d0] = v;
  }
  __syncthreads();
  int d = tid >> 1, ts = (tid & 1) * 32;
  size_t obase = (size_t)(g * 128 + d) * 2048 + t0 + ts;
#pragma unroll
  for (int j = 0; j < 4; j++) {
    bf16x8 o;
#pragma unroll
    for (int e = 0; e < 8; e++) o[e] = (short)tile[ts + j * 8 + e][d];
    *(bf16x8*)&vT[obase + j * 8] = o;
  }
}

// ---------------- flash attention ----------------
// grid: x = q-tile (16), y = head instance (32 = b*16 + h), block 256 (4 waves x 32 rows)
__global__ __launch_bounds__(256, 2) void k_flash(
    const unsigned short* __restrict__ packed,
    const unsigned short* __restrict__ vT,
    unsigned short* __restrict__ Y) {
  __shared__ unsigned short smem[128 * 128];   // Q tile, later K[64][128] | VT[128][64]
  __shared__ unsigned short Ps[4][32 * 72];
  unsigned short* Ks = smem;
  unsigned short* Vs = smem + 64 * 128;
  int tid = threadIdx.x, lane = tid & 63, wid = tid >> 6;
  int row16 = lane & 15, kq = lane >> 4;
  int hi = blockIdx.y;
  int b = hi >> 4, h = hi & 15, kv = h >> 2;
  int qt = blockIdx.x;
  size_t prow = (size_t)b * 2048;

  {  // stage Q [128][128]
    int rr = tid >> 4, cc = (tid & 15) * 8;
    const unsigned short* qg = packed + (prow + qt * 128 + rr) * 3072 + h * 128 + cc;
#pragma unroll
    for (int i = 0; i < 8; i++)
      g2l16(qg + (size_t)i * 16 * 3072, &smem[i * 2048 + tid * 8]);
  }
  __syncthreads();
  bf16x8 q[2][4];
  int qrow = wid * 32;
#pragma unroll
  for (int m = 0; m < 2; m++)
#pragma unroll
    for (int kc = 0; kc < 4; kc++)
      q[m][kc] = *(const bf16x8*)&smem[(qrow + m * 16 + row16) * 128 + kc * 32 + kq * 8];
  __syncthreads();   // Q consumed; smem reused for K/VT

  f32x4 o[2][8] = {};
  float mr[2][4], lr[2][4];
#pragma unroll
  for (int m = 0; m < 2; m++)
#pragma unroll
    for (int j = 0; j < 4; j++) { mr[m][j] = -1e30f; lr[m][j] = 0.f; }
  const float scale = 0.08838834764831845f;  // 1/sqrt(128)
  const float l2e = 1.4426950408889634f;
  const unsigned short* kg0 = packed + prow * 3072 + 2048 + kv * 128;
  const unsigned short* vg0 = vT + (size_t)(b * 4 + kv) * 128 * 2048;

  for (int t0 = 0; t0 < 2048; t0 += 64) {
    {  // stage K [64][128] and VT [128][64]
      int rr = tid >> 4, cc = (tid & 15) * 8;
      const unsigned short* kg = kg0 + (size_t)(t0 + rr) * 3072 + cc;
#pragma unroll
      for (int i = 0; i < 4; i++)
        g2l16(kg + (size_t)i * 16 * 3072, &Ks[i * 2048 + tid * 8]);
      int r2 = tid >> 3, c2 = (tid & 7) * 8;
      const unsigned short* vg = vg0 + (size_t)r2 * 2048 + t0 + c2;
#pragma unroll
      for (int i = 0; i < 4; i++)
        g2l16(vg + (size_t)i * 32 * 2048, &Vs[i * 2048 + tid * 8]);
    }
    __syncthreads();

    // S = Q K^T
    f32x4 s[2][4];
#pragma unroll
    for (int m = 0; m < 2; m++)
#pragma unroll
      for (int n = 0; n < 4; n++) s[m][n] = f32x4{0.f, 0.f, 0.f, 0.f};
#pragma unroll
    for (int n = 0; n < 4; n++) {
      bf16x8 bk[4];
#pragma unroll
      for (int kc = 0; kc < 4; kc++)
        bk[kc] = *(const bf16x8*)&Ks[(n * 16 + row16) * 128 + kc * 32 + kq * 8];
#pragma unroll
      for (int m = 0; m < 2; m++)
#pragma unroll
        for (int kc = 0; kc < 4; kc++)
          s[m][n] = __builtin_amdgcn_mfma_f32_16x16x32_bf16(q[m][kc], bk[kc], s[m][n], 0, 0, 0);
    }
#pragma unroll
    for (int m = 0; m < 2; m++)
#pragma unroll
      for (int n = 0; n < 4; n++) s[m][n] *= scale;

    // online softmax (row r = m*16 + kq*4 + j, spread over 16 lanes)
    float pmax[2][4], al[2][4], rs[2][4];
#pragma unroll
    for (int m = 0; m < 2; m++)
#pragma unroll
      for (int j = 0; j < 4; j++) {
        float v = fmaxf(fmaxf(s[m][0][j], s[m][1][j]), fmaxf(s[m][2][j], s[m][3][j]));
        pmax[m][j] = v;
      }
#pragma unroll
    for (int off = 1; off < 16; off <<= 1)
#pragma unroll
      for (int m = 0; m < 2; m++)
#pragma unroll
        for (int j = 0; j < 4; j++)
          pmax[m][j] = fmaxf(pmax[m][j], __shfl_xor(pmax[m][j], off));
#pragma unroll
    for (int m = 0; m < 2; m++)
#pragma unroll
      for (int j = 0; j < 4; j++) {
        float mn = fmaxf(mr[m][j], pmax[m][j]);
        al[m][j] = exp2f((mr[m][j] - mn) * l2e);
        mr[m][j] = mn;
      }
#pragma unroll
    for (int m = 0; m < 2; m++)
#pragma unroll
      for (int n = 0; n < 4; n++)
#pragma unroll
        for (int j = 0; j < 4; j++)
          s[m][n][j] = exp2f((s[m][n][j] - mr[m][j]) * l2e);
#pragma unroll
    for (int m = 0; m < 2; m++)
#pragma unroll
      for (int j = 0; j < 4; j++)
        rs[m][j] = s[m][0][j] + s[m][1][j] + s[m][2][j] + s[m][3][j];
#pragma unroll
    for (int off = 1; off < 16; off <<= 1)
#pragma unroll
      for (int m = 0; m < 2; m++)
#pragma unroll
        for (int j = 0; j < 4; j++)
          rs[m][j] += __shfl_xor(rs[m][j], off);
#pragma unroll
    for (int m = 0; m < 2; m++)
#pragma unroll
      for (int j = 0; j < 4; j++)
        lr[m][j] = lr[m][j] * al[m][j] + rs[m][j];
#pragma unroll
    for (int m = 0; m < 2; m++)
#pragma unroll
      for (int np = 0; np < 8; np++)
#pragma unroll
        for (int j = 0; j < 4; j++)
          o[m][np][j] *= al[m][j];

    // P -> LDS (per-wave, padded stride 72)
#pragma unroll
    for (int m = 0; m < 2; m++)
#pragma unroll
      for (int n = 0; n < 4; n++)
#pragma unroll
        for (int j = 0; j < 4; j++)
          Ps[wid][(m * 16 + kq * 4 + j) * 72 + n * 16 + row16] = f2bf(s[m][n][j]);

    // O += P V
    bf16x8 pf[2][2];
#pragma unroll
    for (int m = 0; m < 2; m++)
#pragma unroll
      for (int k2 = 0; k2 < 2; k2++)
        pf[m][k2] = *(const bf16x8*)&Ps[wid][(m * 16 + row16) * 72 + k2 * 32 + kq * 8];
#pragma unroll
    for (int np = 0; np < 8; np++) {
      bf16x8 bv0 = *(const bf16x8*)&Vs[(np * 16 + row16) * 64 + kq * 8];
      bf16x8 bv1 = *(const bf16x8*)&Vs[(np * 16 + row16) * 64 + 32 + kq * 8];
#pragma unroll
      for (int m = 0; m < 2; m++) {
        o[m][np] = __builtin_amdgcn_mfma_f32_16x16x32_bf16(pf[m][0], bv0, o[m][np], 0, 0, 0);
        o[m][np] = __builtin_amdgcn_mfma_f32_16x16x32_bf16(pf[m][1], bv1, o[m][np], 0, 0, 0);
      }
    }
    __syncthreads();
  }

  // epilogue: Y[row][h*128+d] = O / l
#pragma unroll
  for (int m = 0; m < 2; m++)
#pragma unroll
    for (int j = 0; j < 4; j++) {
      float inv = 1.f / lr[m][j];
      size_t orow = prow + (size_t)qt * 128 + qrow + m * 16 + kq * 4 + j;
#pragma unroll
      for (int np = 0; np < 8; np++) {
        int ocol = h * 128 + np * 16 + row16;
        Y[orow * 2048 + ocol] = f2bf(o[m][np][j] * inv);
      }
    }
}

extern "C" void kernel_launch(void* const* d_in, const int* in_sizes, int n_in,
                              void* d_out, int out_size, void* d_ws, size_t ws_size,
                              hipStream_t stream) {
  const float* x     = (const float*)d_in[0];
  const float* in_w  = (const float*)d_in[1];
  const float* in_b  = (const float*)d_in[2];
  const float* out_w = (const float*)d_in[3];
  const float* out_b = (const float*)d_in[4];
  float* out = (float*)d_out;

  unsigned short* xb     = (unsigned short*)d_ws;            // 8388608
  unsigned short* wb     = xb + 8388608;                     // 6291456
  unsigned short* owb    = wb + 6291456;                     // 4194304
  unsigned short* packed = owb + 4194304;                    // 12582912
  unsigned short* vt     = packed + 12582912;                // 2097152
  unsigned short* y      = vt + 2097152;                     // 8388608

  k_cvt<<<dim3(1024), dim3(256), 0, stream>>>(x, xb, 8388608 / 4);
  k_cvt<<<dim3(1024), dim3(256), 0, stream>>>(in_w, wb, 6291456 / 4);
  k_cvt<<<dim3(1024), dim3(256), 0, stream>>>(out_w, owb, 4194304 / 4);

  k_gemm<true><<<dim3(24, 32), dim3(256), 0, stream>>>(xb, wb, in_b, packed, 4096, 3072, 2048);
  k_vt<<<dim3(32, 8), dim3(256), 0, stream>>>(packed, vt);
  k_flash<<<dim3(16, 32), dim3(256), 0, stream>>>(packed, vt, y);
  k_gemm<false><<<dim3(16, 32), dim3(256), 0, stream>>>(y, owb, out_b, out, 4096, 2048, 2048);
}

// Round 2
// 275.843 us; speedup vs baseline: 1.2034x; 1.2034x over previous
//
#include <hip/hip_runtime.h>
#include <hip/hip_bf16.h>
#include <stdint.h>

#define DEV __device__ __forceinline__

typedef __attribute__((ext_vector_type(8))) short bf16x8;
typedef __attribute__((ext_vector_type(4))) float f32x4;

DEV unsigned short f2bf(float f) {
  unsigned u = __builtin_bit_cast(unsigned, f);
  unsigned r = u + 0x7FFF + ((u >> 16) & 1);   // RNE
  return (unsigned short)(r >> 16);
}

typedef __attribute__((address_space(1))) void gvoid;
typedef __attribute__((address_space(3))) void lvoid;

DEV void g2l16(const void* g, void* l) {
  __builtin_amdgcn_global_load_lds((gvoid*)g, (lvoid*)l, 16, 0, 0);
}

// ---------------- fp32 -> bf16 convert ----------------
__global__ void k_cvt(const float* __restrict__ in, unsigned short* __restrict__ out, int n4) {
  int i = blockIdx.x * blockDim.x + threadIdx.x;
  int stride = gridDim.x * blockDim.x;
  for (; i < n4; i += stride) {
    float4 v = reinterpret_cast<const float4*>(in)[i];
    ushort4 o;
    o.x = f2bf(v.x); o.y = f2bf(v.y); o.z = f2bf(v.z); o.w = f2bf(v.w);
    reinterpret_cast<ushort4*>(out)[i] = o;
  }
}

// ---------------- 128x128 tile bf16 GEMM, B given as B^T [N][K], +bias ----------------
template<bool BF16OUT>
__global__ __launch_bounds__(256, 2) void k_gemm(
    const unsigned short* __restrict__ A, const unsigned short* __restrict__ B,
    const float* __restrict__ bias, void* __restrict__ C,
    int M, int N, int K) {
  __shared__ unsigned short As[128 * 32];
  __shared__ unsigned short Bs[128 * 32];
  int tid = threadIdx.x;
  int lane = tid & 63, wid = tid >> 6;
  int bm = blockIdx.y * 128, bn = blockIdx.x * 128;
  int wm = (wid >> 1) * 64, wn = (wid & 1) * 64;
  int row16 = lane & 15, kq = lane >> 4;
  f32x4 acc[4][4] = {};
  int r = tid >> 2, c = (tid & 3) * 8;
  const unsigned short* Ag = A + (size_t)(bm + r) * K + c;
  const unsigned short* Bg = B + (size_t)(bn + r) * K + c;
  for (int k0 = 0; k0 < K; k0 += 32) {
    g2l16(Ag + k0, &As[tid * 8]);
    g2l16(Ag + (size_t)64 * K + k0, &As[2048 + tid * 8]);
    g2l16(Bg + k0, &Bs[tid * 8]);
    g2l16(Bg + (size_t)64 * K + k0, &Bs[2048 + tid * 8]);
    __syncthreads();
    bf16x8 a[4], b[4];
#pragma unroll
    for (int m = 0; m < 4; m++) a[m] = *(const bf16x8*)&As[(wm + m * 16 + row16) * 32 + kq * 8];
#pragma unroll
    for (int n = 0; n < 4; n++) b[n] = *(const bf16x8*)&Bs[(wn + n * 16 + row16) * 32 + kq * 8];
    __builtin_amdgcn_s_setprio(1);
#pragma unroll
    for (int m = 0; m < 4; m++)
#pragma unroll
      for (int n = 0; n < 4; n++)
        acc[m][n] = __builtin_amdgcn_mfma_f32_16x16x32_bf16(a[m], b[n], acc[m][n], 0, 0, 0);
    __builtin_amdgcn_s_setprio(0);
    __syncthreads();
  }
#pragma unroll
  for (int n = 0; n < 4; n++) {
    int col = bn + wn + n * 16 + row16;
    float bv = bias[col];
#pragma unroll
    for (int m = 0; m < 4; m++) {
      int rw = bm + wm + m * 16 + kq * 4;
#pragma unroll
      for (int j = 0; j < 4; j++) {
        float v = acc[m][n][j] + bv;
        if (BF16OUT) ((unsigned short*)C)[(size_t)(rw + j) * N + col] = f2bf(v);
        else         ((float*)C)[(size_t)(rw + j) * N + col] = v;
      }
    }
  }
}

// ---------------- V transpose: packed[b,t,2560+kv*128+d] -> vT[(b*4+kv)*128+d][t] ----------------
__global__ void k_vt(const unsigned short* __restrict__ packed, unsigned short* __restrict__ vT) {
  __shared__ unsigned short tile[64][136];
  int g = blockIdx.y;            // b*4+kv
  int b = g >> 2, kv = g & 3;
  int t0 = blockIdx.x * 64;
  int tid = threadIdx.x;
#pragma unroll
  for (int i = 0; i < 4; i++) {
    int tl = i * 16 + (tid >> 4);
    int d0 = (tid & 15) * 8;
    bf16x8 v = *(const bf16x8*)&packed[(size_t)(b * 2048 + t0 + tl) * 3072 + 2560 + kv * 128 + d0];
    *(bf16x8*)&tile[tl][d0] = v;
  }
  __syncthreads();
  int d = tid >> 1, ts = (tid & 1) * 32;
  size_t obase = (size_t)(g * 128 + d) * 2048 + t0 + ts;
#pragma unroll
  for (int j = 0; j < 4; j++) {
    bf16x8 o;
#pragma unroll
    for (int e = 0; e < 8; e++) o[e] = (short)tile[ts + j * 8 + e][d];
    *(bf16x8*)&vT[obase + j * 8] = o;
  }
}

// ---------------- flash attention ----------------
// grid: x = q-tile (16), y = head instance (32 = b*16 + h), block 256 (4 waves x 32 rows)
// LDS tiles XOR-swizzled: 16B slot index ^= (row & 7); staged via pre-swizzled
// global source (global_load_lds dest must stay linear), read with same XOR.
__global__ __launch_bounds__(256, 2) void k_flash(
    const unsigned short* __restrict__ packed,
    const unsigned short* __restrict__ vT,
    unsigned short* __restrict__ Y) {
  __shared__ unsigned short smem[128 * 128];   // Q tile, later K[64][128] | VT[128][64]
  __shared__ unsigned short Ps[4][32 * 72];
  unsigned short* Ks = smem;
  unsigned short* Vs = smem + 64 * 128;
  int tid = threadIdx.x, lane = tid & 63, wid = tid >> 6;
  int row16 = lane & 15, kq = lane >> 4;
  int r3 = row16 & 7;                          // swizzle key for reads
  int hi = blockIdx.y;
  int b = hi >> 4, h = hi & 15, kv = h >> 2;
  int qt = blockIdx.x;
  size_t prow = (size_t)b * 2048;

  {  // stage Q [128][128] swizzled
    int rr = tid >> 4;
    int cc = ((tid & 15) ^ (rr & 7)) * 8;      // pre-swizzled source column
    const unsigned short* qg = packed + (prow + qt * 128 + rr) * 3072 + h * 128 + cc;
#pragma unroll
    for (int i = 0; i < 8; i++)
      g2l16(qg + (size_t)i * 16 * 3072, &smem[i * 2048 + tid * 8]);
  }
  __syncthreads();
  bf16x8 q[2][4];
  int qrow = wid * 32;
#pragma unroll
  for (int m = 0; m < 2; m++)
#pragma unroll
    for (int kc = 0; kc < 4; kc++)
      q[m][kc] = *(const bf16x8*)&smem[(qrow + m * 16 + row16) * 128 + (((kc * 4 + kq) ^ r3) * 8)];
  __syncthreads();   // Q consumed; smem reused for K/VT

  f32x4 o[2][8] = {};
  float mr[2][4], lr[2][4];
#pragma unroll
  for (int m = 0; m < 2; m++)
#pragma unroll
    for (int j = 0; j < 4; j++) { mr[m][j] = -1e30f; lr[m][j] = 0.f; }
  const float sc2 = 0.08838834764831845f * 1.4426950408889634f;  // scale * log2(e)
  const unsigned short* kg0 = packed + prow * 3072 + 2048 + kv * 128;
  const unsigned short* vg0 = vT + (size_t)(b * 4 + kv) * 128 * 2048;

  // per-lane pre-swizzled staging source columns (row&7 is i-invariant)
  int krr = tid >> 4;
  int kcc = ((tid & 15) ^ (krr & 7)) * 8;
  int vrr = tid >> 3;
  int vcc = ((tid & 7) ^ (vrr & 7)) * 8;

  for (int t0 = 0; t0 < 2048; t0 += 64) {
    {  // stage K [64][128] and VT [128][64], swizzled
      const unsigned short* kg = kg0 + (size_t)(t0 + krr) * 3072 + kcc;
#pragma unroll
      for (int i = 0; i < 4; i++)
        g2l16(kg + (size_t)i * 16 * 3072, &Ks[i * 2048 + tid * 8]);
      const unsigned short* vg = vg0 + (size_t)vrr * 2048 + t0 + vcc;
#pragma unroll
      for (int i = 0; i < 4; i++)
        g2l16(vg + (size_t)i * 32 * 2048, &Vs[i * 2048 + tid * 8]);
    }
    __syncthreads();

    // S = Q K^T
    f32x4 s[2][4];
#pragma unroll
    for (int m = 0; m < 2; m++)
#pragma unroll
      for (int n = 0; n < 4; n++) s[m][n] = f32x4{0.f, 0.f, 0.f, 0.f};
#pragma unroll
    for (int n = 0; n < 4; n++) {
      bf16x8 bk[4];
#pragma unroll
      for (int kc = 0; kc < 4; kc++)
        bk[kc] = *(const bf16x8*)&Ks[(n * 16 + row16) * 128 + (((kc * 4 + kq) ^ r3) * 8)];
      __builtin_amdgcn_s_setprio(1);
#pragma unroll
      for (int m = 0; m < 2; m++)
#pragma unroll
        for (int kc = 0; kc < 4; kc++)
          s[m][n] = __builtin_amdgcn_mfma_f32_16x16x32_bf16(q[m][kc], bk[kc], s[m][n], 0, 0, 0);
      __builtin_amdgcn_s_setprio(0);
    }
    // scale into log2 domain
#pragma unroll
    for (int m = 0; m < 2; m++)
#pragma unroll
      for (int n = 0; n < 4; n++) s[m][n] *= sc2;

    // online softmax in log2 domain (row r = m*16 + kq*4 + j, spread over 16 lanes)
    float pmax[2][4], al[2][4], rs[2][4];
#pragma unroll
    for (int m = 0; m < 2; m++)
#pragma unroll
      for (int j = 0; j < 4; j++)
        pmax[m][j] = fmaxf(fmaxf(s[m][0][j], s[m][1][j]), fmaxf(s[m][2][j], s[m][3][j]));
#pragma unroll
    for (int off = 1; off < 16; off <<= 1)
#pragma unroll
      for (int m = 0; m < 2; m++)
#pragma unroll
        for (int j = 0; j < 4; j++)
          pmax[m][j] = fmaxf(pmax[m][j], __shfl_xor(pmax[m][j], off));
#pragma unroll
    for (int m = 0; m < 2; m++)
#pragma unroll
      for (int j = 0; j < 4; j++) {
        float mn = fmaxf(mr[m][j], pmax[m][j]);
        al[m][j] = exp2f(mr[m][j] - mn);
        mr[m][j] = mn;
      }
#pragma unroll
    for (int m = 0; m < 2; m++)
#pragma unroll
      for (int n = 0; n < 4; n++)
#pragma unroll
        for (int j = 0; j < 4; j++)
          s[m][n][j] = exp2f(s[m][n][j] - mr[m][j]);
#pragma unroll
    for (int m = 0; m < 2; m++)
#pragma unroll
      for (int j = 0; j < 4; j++)
        rs[m][j] = s[m][0][j] + s[m][1][j] + s[m][2][j] + s[m][3][j];
#pragma unroll
    for (int off = 1; off < 16; off <<= 1)
#pragma unroll
      for (int m = 0; m < 2; m++)
#pragma unroll
        for (int j = 0; j < 4; j++)
          rs[m][j] += __shfl_xor(rs[m][j], off);
#pragma unroll
    for (int m = 0; m < 2; m++)
#pragma unroll
      for (int j = 0; j < 4; j++)
        lr[m][j] = lr[m][j] * al[m][j] + rs[m][j];
#pragma unroll
    for (int m = 0; m < 2; m++)
#pragma unroll
      for (int np = 0; np < 8; np++)
#pragma unroll
        for (int j = 0; j < 4; j++)
          o[m][np][j] *= al[m][j];

    // P -> LDS (per-wave, padded stride 72)
#pragma unroll
    for (int m = 0; m < 2; m++)
#pragma unroll
      for (int n = 0; n < 4; n++)
#pragma unroll
        for (int j = 0; j < 4; j++)
          Ps[wid][(m * 16 + kq * 4 + j) * 72 + n * 16 + row16] = f2bf(s[m][n][j]);

    // O += P V
    bf16x8 pf[2][2];
#pragma unroll
    for (int m = 0; m < 2; m++)
#pragma unroll
      for (int k2 = 0; k2 < 2; k2++)
        pf[m][k2] = *(const bf16x8*)&Ps[wid][(m * 16 + row16) * 72 + k2 * 32 + kq * 8];
#pragma unroll
    for (int np = 0; np < 8; np++) {
      int vrow = np * 16 + row16;
      bf16x8 bv0 = *(const bf16x8*)&Vs[vrow * 64 + ((kq ^ r3) * 8)];
      bf16x8 bv1 = *(const bf16x8*)&Vs[vrow * 64 + (((4 + kq) ^ r3) * 8)];
      __builtin_amdgcn_s_setprio(1);
#pragma unroll
      for (int m = 0; m < 2; m++) {
        o[m][np] = __builtin_amdgcn_mfma_f32_16x16x32_bf16(pf[m][0], bv0, o[m][np], 0, 0, 0);
        o[m][np] = __builtin_amdgcn_mfma_f32_16x16x32_bf16(pf[m][1], bv1, o[m][np], 0, 0, 0);
      }
      __builtin_amdgcn_s_setprio(0);
    }
    __syncthreads();
  }

  // epilogue: Y[row][h*128+d] = O / l
#pragma unroll
  for (int m = 0; m < 2; m++)
#pragma unroll
    for (int j = 0; j < 4; j++) {
      float inv = 1.f / lr[m][j];
      size_t orow = prow + (size_t)qt * 128 + qrow + m * 16 + kq * 4 + j;
#pragma unroll
      for (int np = 0; np < 8; np++) {
        int ocol = h * 128 + np * 16 + row16;
        Y[orow * 2048 + ocol] = f2bf(o[m][np][j] * inv);
      }
    }
}

extern "C" void kernel_launch(void* const* d_in, const int* in_sizes, int n_in,
                              void* d_out, int out_size, void* d_ws, size_t ws_size,
                              hipStream_t stream) {
  const float* x     = (const float*)d_in[0];
  const float* in_w  = (const float*)d_in[1];
  const float* in_b  = (const float*)d_in[2];
  const float* out_w = (const float*)d_in[3];
  const float* out_b = (const float*)d_in[4];
  float* out = (float*)d_out;

  unsigned short* xb     = (unsigned short*)d_ws;            // 8388608
  unsigned short* wb     = xb + 8388608;                     // 6291456
  unsigned short* owb    = wb + 6291456;                     // 4194304
  unsigned short* packed = owb + 4194304;                    // 12582912
  unsigned short* vt     = packed + 12582912;                // 2097152
  unsigned short* y      = vt + 2097152;                     // 8388608

  k_cvt<<<dim3(1024), dim3(256), 0, stream>>>(x, xb, 8388608 / 4);
  k_cvt<<<dim3(1024), dim3(256), 0, stream>>>(in_w, wb, 6291456 / 4);
  k_cvt<<<dim3(1024), dim3(256), 0, stream>>>(out_w, owb, 4194304 / 4);

  k_gemm<true><<<dim3(24, 32), dim3(256), 0, stream>>>(xb, wb, in_b, packed, 4096, 3072, 2048);
  k_vt<<<dim3(32, 8), dim3(256), 0, stream>>>(packed, vt);
  k_flash<<<dim3(16, 32), dim3(256), 0, stream>>>(packed, vt, y);
  k_gemm<false><<<dim3(16, 32), dim3(256), 0, stream>>>(y, owb, out_b, out, 4096, 2048, 2048);
}

// Round 3
// 264.579 us; speedup vs baseline: 1.2547x; 1.0426x over previous
//
#include <hip/hip_runtime.h>
#include <hip/hip_bf16.h>
#include <stdint.h>

#define DEV __device__ __forceinline__

typedef __attribute__((ext_vector_type(8))) short bf16x8;
typedef __attribute__((ext_vector_type(4))) float f32x4;

DEV unsigned short f2bf(float f) {
  unsigned u = __builtin_bit_cast(unsigned, f);
  unsigned r = u + 0x7FFF + ((u >> 16) & 1);   // RNE
  return (unsigned short)(r >> 16);
}

typedef __attribute__((address_space(1))) void gvoid;
typedef __attribute__((address_space(3))) void lvoid;

DEV void g2l16(const void* g, void* l) {
  __builtin_amdgcn_global_load_lds((gvoid*)g, (lvoid*)l, 16, 0, 0);
}

// ---------------- fp32 -> bf16 convert ----------------
__global__ void k_cvt(const float* __restrict__ in, unsigned short* __restrict__ out, int n4) {
  int i = blockIdx.x * blockDim.x + threadIdx.x;
  int stride = gridDim.x * blockDim.x;
  for (; i < n4; i += stride) {
    float4 v = reinterpret_cast<const float4*>(in)[i];
    ushort4 o;
    o.x = f2bf(v.x); o.y = f2bf(v.y); o.z = f2bf(v.z); o.w = f2bf(v.w);
    reinterpret_cast<ushort4*>(out)[i] = o;
  }
}

// ---------------- 128x128 tile bf16 GEMM, B given as B^T [N][K], +bias ----------------
template<bool BF16OUT>
__global__ __launch_bounds__(256, 2) void k_gemm(
    const unsigned short* __restrict__ A, const unsigned short* __restrict__ B,
    const float* __restrict__ bias, void* __restrict__ C,
    int M, int N, int K) {
  __shared__ unsigned short As[128 * 32];
  __shared__ unsigned short Bs[128 * 32];
  int tid = threadIdx.x;
  int lane = tid & 63, wid = tid >> 6;
  int bm = blockIdx.y * 128, bn = blockIdx.x * 128;
  int wm = (wid >> 1) * 64, wn = (wid & 1) * 64;
  int row16 = lane & 15, kq = lane >> 4;
  f32x4 acc[4][4] = {};
  int r = tid >> 2, c = (tid & 3) * 8;
  const unsigned short* Ag = A + (size_t)(bm + r) * K + c;
  const unsigned short* Bg = B + (size_t)(bn + r) * K + c;
  for (int k0 = 0; k0 < K; k0 += 32) {
    g2l16(Ag + k0, &As[tid * 8]);
    g2l16(Ag + (size_t)64 * K + k0, &As[2048 + tid * 8]);
    g2l16(Bg + k0, &Bs[tid * 8]);
    g2l16(Bg + (size_t)64 * K + k0, &Bs[2048 + tid * 8]);
    __syncthreads();
    bf16x8 a[4], b[4];
#pragma unroll
    for (int m = 0; m < 4; m++) a[m] = *(const bf16x8*)&As[(wm + m * 16 + row16) * 32 + kq * 8];
#pragma unroll
    for (int n = 0; n < 4; n++) b[n] = *(const bf16x8*)&Bs[(wn + n * 16 + row16) * 32 + kq * 8];
    __builtin_amdgcn_s_setprio(1);
#pragma unroll
    for (int m = 0; m < 4; m++)
#pragma unroll
      for (int n = 0; n < 4; n++)
        acc[m][n] = __builtin_amdgcn_mfma_f32_16x16x32_bf16(a[m], b[n], acc[m][n], 0, 0, 0);
    __builtin_amdgcn_s_setprio(0);
    __syncthreads();
  }
#pragma unroll
  for (int n = 0; n < 4; n++) {
    int col = bn + wn + n * 16 + row16;
    float bv = bias[col];
#pragma unroll
    for (int m = 0; m < 4; m++) {
      int rw = bm + wm + m * 16 + kq * 4;
#pragma unroll
      for (int j = 0; j < 4; j++) {
        float v = acc[m][n][j] + bv;
        if (BF16OUT) ((unsigned short*)C)[(size_t)(rw + j) * N + col] = f2bf(v);
        else         ((float*)C)[(size_t)(rw + j) * N + col] = v;
      }
    }
  }
}

// ---------------- V transpose: packed[b,t,2560+kv*128+d] -> vT[(b*4+kv)*128+d][t] ----------------
__global__ void k_vt(const unsigned short* __restrict__ packed, unsigned short* __restrict__ vT) {
  __shared__ unsigned short tile[64][136];
  int g = blockIdx.y;            // b*4+kv
  int b = g >> 2, kv = g & 3;
  int t0 = blockIdx.x * 64;
  int tid = threadIdx.x;
#pragma unroll
  for (int i = 0; i < 4; i++) {
    int tl = i * 16 + (tid >> 4);
    int d0 = (tid & 15) * 8;
    bf16x8 v = *(const bf16x8*)&packed[(size_t)(b * 2048 + t0 + tl) * 3072 + 2560 + kv * 128 + d0];
    *(bf16x8*)&tile[tl][d0] = v;
  }
  __syncthreads();
  int d = tid >> 1, ts = (tid & 1) * 32;
  size_t obase = (size_t)(g * 128 + d) * 2048 + t0 + ts;
#pragma unroll
  for (int j = 0; j < 4; j++) {
    bf16x8 o;
#pragma unroll
    for (int e = 0; e < 8; e++) o[e] = (short)tile[ts + j * 8 + e][d];
    *(bf16x8*)&vT[obase + j * 8] = o;
  }
}

// ---------------- flash attention ----------------
// grid: x = q-tile (32 x 64 rows), y = head instance (32 = b*16 + h), block 256
// (4 waves x 16 q-rows). Swapped QK^T: S^T = mfma(K_frag, Q_frag) so q is
// lane-local (col = lane&15) -> row max/sum = in-lane fold + 2 shfl_xor.
// LDS tiles XOR-swizzled (slot ^= row&7), staged via pre-swizzled global src.
__global__ __launch_bounds__(256, 2) void k_flash(
    const unsigned short* __restrict__ packed,
    const unsigned short* __restrict__ vT,
    unsigned short* __restrict__ Y) {
  __shared__ unsigned short smem[64 * 128 + 128 * 64];   // Q(64x128) then K[64][128] | VT[128][64]
  __shared__ unsigned short Ps[4][16 * 72];              // per-wave P [16 q][64 kv], stride 72
  __shared__ float Axc[4][16];                           // per-wave alpha / l exchange
  unsigned short* Ks = smem;
  unsigned short* Vs = smem + 64 * 128;
  int tid = threadIdx.x, lane = tid & 63, wid = tid >> 6;
  int row16 = lane & 15, kq = lane >> 4;
  int r3 = row16 & 7;                          // swizzle key for reads
  int hi = blockIdx.y;
  int b = hi >> 4, h = hi & 15, kv = h >> 2;
  int qt = blockIdx.x;
  size_t prow = (size_t)b * 2048;

  {  // stage Q [64][128] swizzled (into Ks region)
    int rr = tid >> 4;
    int cc = ((tid & 15) ^ (rr & 7)) * 8;      // pre-swizzled source column
    const unsigned short* qg = packed + (prow + qt * 64 + rr) * 3072 + h * 128 + cc;
#pragma unroll
    for (int i = 0; i < 4; i++)
      g2l16(qg + (size_t)i * 16 * 3072, &Ks[i * 2048 + tid * 8]);
  }
  __syncthreads();
  bf16x8 q[4];
  int qrow = wid * 16;
#pragma unroll
  for (int kc = 0; kc < 4; kc++)
    q[kc] = *(const bf16x8*)&Ks[(qrow + row16) * 128 + (((kc * 4 + kq) ^ r3) * 8)];
  __syncthreads();   // Q consumed; smem reused for K/VT

  f32x4 o[8] = {};
  float mr = -1e30f, lr = 0.f;
  const float sc2 = 0.08838834764831845f * 1.4426950408889634f;  // scale * log2(e)
  const unsigned short* kg0 = packed + prow * 3072 + 2048 + kv * 128;
  const unsigned short* vg0 = vT + (size_t)(b * 4 + kv) * 128 * 2048;

  // per-lane pre-swizzled staging source columns (row&7 is i-invariant)
  int krr = tid >> 4;
  int kcc = ((tid & 15) ^ (krr & 7)) * 8;
  int vrr = tid >> 3;
  int vcc = ((tid & 7) ^ (vrr & 7)) * 8;

  for (int t0 = 0; t0 < 2048; t0 += 64) {
    {  // stage K [64][128] and VT [128][64], swizzled
      const unsigned short* kg = kg0 + (size_t)(t0 + krr) * 3072 + kcc;
#pragma unroll
      for (int i = 0; i < 4; i++)
        g2l16(kg + (size_t)i * 16 * 3072, &Ks[i * 2048 + tid * 8]);
      const unsigned short* vg = vg0 + (size_t)vrr * 2048 + t0 + vcc;
#pragma unroll
      for (int i = 0; i < 4; i++)
        g2l16(vg + (size_t)i * 32 * 2048, &Vs[i * 2048 + tid * 8]);
    }
    __syncthreads();

    // S^T = K Q^T : st[mk] rows = kv (mk*16 + kq*4 + j), col = q (row16)
    f32x4 st[4];
#pragma unroll
    for (int mk = 0; mk < 4; mk++) {
      st[mk] = f32x4{0.f, 0.f, 0.f, 0.f};
      bf16x8 bk[4];
#pragma unroll
      for (int kc = 0; kc < 4; kc++)
        bk[kc] = *(const bf16x8*)&Ks[(mk * 16 + row16) * 128 + (((kc * 4 + kq) ^ r3) * 8)];
      __builtin_amdgcn_s_setprio(1);
#pragma unroll
      for (int kc = 0; kc < 4; kc++)
        st[mk] = __builtin_amdgcn_mfma_f32_16x16x32_bf16(bk[kc], q[kc], st[mk], 0, 0, 0);
      __builtin_amdgcn_s_setprio(0);
    }

    // scale into log2 domain
#pragma unroll
    for (int mk = 0; mk < 4; mk++) st[mk] *= sc2;

    // online softmax: q is lane-local; kv spread over regs + kq lane groups
    float pmax = -1e30f;
#pragma unroll
    for (int mk = 0; mk < 4; mk++)
#pragma unroll
      for (int j = 0; j < 4; j++) pmax = fmaxf(pmax, st[mk][j]);
    pmax = fmaxf(pmax, __shfl_xor(pmax, 16));
    pmax = fmaxf(pmax, __shfl_xor(pmax, 32));

    if (!__all(pmax <= mr + 8.f)) {   // defer-max: skip rescale when growth small
      float mn = fmaxf(mr, pmax);
      float al = exp2f(mr - mn);
      mr = mn;
      lr *= al;
      if (lane < 16) Axc[wid][row16] = al;
      float alo[4];
#pragma unroll
      for (int j = 0; j < 4; j++) alo[j] = Axc[wid][kq * 4 + j];
#pragma unroll
      for (int np = 0; np < 8; np++)
#pragma unroll
        for (int j = 0; j < 4; j++) o[np][j] *= alo[j];
    }

    float rs = 0.f;
#pragma unroll
    for (int mk = 0; mk < 4; mk++)
#pragma unroll
      for (int j = 0; j < 4; j++) {
        st[mk][j] = exp2f(st[mk][j] - mr);
        rs += st[mk][j];
      }
    rs += __shfl_xor(rs, 16);
    rs += __shfl_xor(rs, 32);
    lr += rs;

    // P -> LDS: P[q=row16][kv=mk*16+kq*4+j], packed ds_write_b64
#pragma unroll
    for (int mk = 0; mk < 4; mk++) {
      ushort4 pw;
      pw.x = f2bf(st[mk][0]); pw.y = f2bf(st[mk][1]);
      pw.z = f2bf(st[mk][2]); pw.w = f2bf(st[mk][3]);
      *(ushort4*)&Ps[wid][row16 * 72 + mk * 16 + kq * 4] = pw;
    }

    // O += P V   (A-frag: row=q=row16, k = k2*32 + kq*8 + j : contiguous b128)
    bf16x8 pf[2];
#pragma unroll
    for (int k2 = 0; k2 < 2; k2++)
      pf[k2] = *(const bf16x8*)&Ps[wid][row16 * 72 + k2 * 32 + kq * 8];
#pragma unroll
    for (int np = 0; np < 8; np++) {
      int vrow = np * 16 + row16;
      bf16x8 bv0 = *(const bf16x8*)&Vs[vrow * 64 + ((kq ^ r3) * 8)];
      bf16x8 bv1 = *(const bf16x8*)&Vs[vrow * 64 + (((4 + kq) ^ r3) * 8)];
      __builtin_amdgcn_s_setprio(1);
      o[np] = __builtin_amdgcn_mfma_f32_16x16x32_bf16(pf[0], bv0, o[np], 0, 0, 0);
      o[np] = __builtin_amdgcn_mfma_f32_16x16x32_bf16(pf[1], bv1, o[np], 0, 0, 0);
      __builtin_amdgcn_s_setprio(0);
    }
    __syncthreads();
  }

  // epilogue: redistribute l (softmax layout q=row16 -> O layout q=kq*4+j)
  if (lane < 16) Axc[wid][row16] = lr;
#pragma unroll
  for (int j = 0; j < 4; j++) {
    float inv = 1.f / Axc[wid][kq * 4 + j];
    size_t orow = prow + (size_t)qt * 64 + qrow + kq * 4 + j;
#pragma unroll
    for (int np = 0; np < 8; np++)
      Y[orow * 2048 + h * 128 + np * 16 + row16] = f2bf(o[np][j] * inv);
  }
}

extern "C" void kernel_launch(void* const* d_in, const int* in_sizes, int n_in,
                              void* d_out, int out_size, void* d_ws, size_t ws_size,
                              hipStream_t stream) {
  const float* x     = (const float*)d_in[0];
  const float* in_w  = (const float*)d_in[1];
  const float* in_b  = (const float*)d_in[2];
  const float* out_w = (const float*)d_in[3];
  const float* out_b = (const float*)d_in[4];
  float* out = (float*)d_out;

  unsigned short* xb     = (unsigned short*)d_ws;            // 8388608
  unsigned short* wb     = xb + 8388608;                     // 6291456
  unsigned short* owb    = wb + 6291456;                     // 4194304
  unsigned short* packed = owb + 4194304;                    // 12582912
  unsigned short* vt     = packed + 12582912;                // 2097152
  unsigned short* y      = vt + 2097152;                     // 8388608

  k_cvt<<<dim3(1024), dim3(256), 0, stream>>>(x, xb, 8388608 / 4);
  k_cvt<<<dim3(1024), dim3(256), 0, stream>>>(in_w, wb, 6291456 / 4);
  k_cvt<<<dim3(1024), dim3(256), 0, stream>>>(out_w, owb, 4194304 / 4);

  k_gemm<true><<<dim3(24, 32), dim3(256), 0, stream>>>(xb, wb, in_b, packed, 4096, 3072, 2048);
  k_vt<<<dim3(32, 8), dim3(256), 0, stream>>>(packed, vt);
  k_flash<<<dim3(32, 32), dim3(256), 0, stream>>>(packed, vt, y);
  k_gemm<false><<<dim3(16, 32), dim3(256), 0, stream>>>(y, owb, out_b, out, 4096, 2048, 2048);
}

// Round 4
// 236.841 us; speedup vs baseline: 1.4016x; 1.1171x over previous
//
#include <hip/hip_runtime.h>
#include <hip/hip_bf16.h>
#include <stdint.h>

#define DEV __device__ __forceinline__

typedef __attribute__((ext_vector_type(8))) short bf16x8;
typedef __attribute__((ext_vector_type(4))) float f32x4;

DEV unsigned short f2bf(float f) {
  unsigned u = __builtin_bit_cast(unsigned, f);
  unsigned r = u + 0x7FFF + ((u >> 16) & 1);   // RNE
  return (unsigned short)(r >> 16);
}

typedef __attribute__((address_space(1))) void gvoid;
typedef __attribute__((address_space(3))) void lvoid;

DEV void g2l16(const void* g, void* l) {
  __builtin_amdgcn_global_load_lds((gvoid*)g, (lvoid*)l, 16, 0, 0);
}

#define MFMA16(a, b, c) __builtin_amdgcn_mfma_f32_16x16x32_bf16(a, b, c, 0, 0, 0)

// ---------------- fp32 -> bf16 convert ----------------
__global__ void k_cvt(const float* __restrict__ in, unsigned short* __restrict__ out, int n4) {
  int i = blockIdx.x * blockDim.x + threadIdx.x;
  int stride = gridDim.x * blockDim.x;
  for (; i < n4; i += stride) {
    float4 v = reinterpret_cast<const float4*>(in)[i];
    ushort4 o;
    o.x = f2bf(v.x); o.y = f2bf(v.y); o.z = f2bf(v.z); o.w = f2bf(v.w);
    reinterpret_cast<ushort4*>(out)[i] = o;
  }
}

// ---------------- 128x128 tile bf16 GEMM, B given as B^T [N][K], +bias ----------------
template<bool BF16OUT>
__global__ __launch_bounds__(256, 2) void k_gemm(
    const unsigned short* __restrict__ A, const unsigned short* __restrict__ B,
    const float* __restrict__ bias, void* __restrict__ C,
    int M, int N, int K) {
  __shared__ unsigned short As[128 * 32];
  __shared__ unsigned short Bs[128 * 32];
  int tid = threadIdx.x;
  int lane = tid & 63, wid = tid >> 6;
  int bm = blockIdx.y * 128, bn = blockIdx.x * 128;
  int wm = (wid >> 1) * 64, wn = (wid & 1) * 64;
  int row16 = lane & 15, kq = lane >> 4;
  f32x4 acc[4][4] = {};
  int r = tid >> 2, c = (tid & 3) * 8;
  const unsigned short* Ag = A + (size_t)(bm + r) * K + c;
  const unsigned short* Bg = B + (size_t)(bn + r) * K + c;
  for (int k0 = 0; k0 < K; k0 += 32) {
    g2l16(Ag + k0, &As[tid * 8]);
    g2l16(Ag + (size_t)64 * K + k0, &As[2048 + tid * 8]);
    g2l16(Bg + k0, &Bs[tid * 8]);
    g2l16(Bg + (size_t)64 * K + k0, &Bs[2048 + tid * 8]);
    __syncthreads();
    bf16x8 a[4], b[4];
#pragma unroll
    for (int m = 0; m < 4; m++) a[m] = *(const bf16x8*)&As[(wm + m * 16 + row16) * 32 + kq * 8];
#pragma unroll
    for (int n = 0; n < 4; n++) b[n] = *(const bf16x8*)&Bs[(wn + n * 16 + row16) * 32 + kq * 8];
    __builtin_amdgcn_s_setprio(1);
#pragma unroll
    for (int m = 0; m < 4; m++)
#pragma unroll
      for (int n = 0; n < 4; n++)
        acc[m][n] = MFMA16(a[m], b[n], acc[m][n]);
    __builtin_amdgcn_s_setprio(0);
    __syncthreads();
  }
#pragma unroll
  for (int n = 0; n < 4; n++) {
    int col = bn + wn + n * 16 + row16;
    float bv = bias[col];
#pragma unroll
    for (int m = 0; m < 4; m++) {
      int rw = bm + wm + m * 16 + kq * 4;
#pragma unroll
      for (int j = 0; j < 4; j++) {
        float v = acc[m][n][j] + bv;
        if (BF16OUT) ((unsigned short*)C)[(size_t)(rw + j) * N + col] = f2bf(v);
        else         ((float*)C)[(size_t)(rw + j) * N + col] = v;
      }
    }
  }
}

// ---------------- V transpose: packed[b,t,2560+kv*128+d] -> vT[(b*4+kv)*128+d][t] ----------------
__global__ void k_vt(const unsigned short* __restrict__ packed, unsigned short* __restrict__ vT) {
  __shared__ unsigned short tile[64][136];
  int g = blockIdx.y;            // b*4+kv
  int b = g >> 2, kv = g & 3;
  int t0 = blockIdx.x * 64;
  int tid = threadIdx.x;
#pragma unroll
  for (int i = 0; i < 4; i++) {
    int tl = i * 16 + (tid >> 4);
    int d0 = (tid & 15) * 8;
    bf16x8 v = *(const bf16x8*)&packed[(size_t)(b * 2048 + t0 + tl) * 3072 + 2560 + kv * 128 + d0];
    *(bf16x8*)&tile[tl][d0] = v;
  }
  __syncthreads();
  int d = tid >> 1, ts = (tid & 1) * 32;
  size_t obase = (size_t)(g * 128 + d) * 2048 + t0 + ts;
#pragma unroll
  for (int j = 0; j < 4; j++) {
    bf16x8 o;
#pragma unroll
    for (int e = 0; e < 8; e++) o[e] = (short)tile[ts + j * 8 + e][d];
    *(bf16x8*)&vT[obase + j * 8] = o;
  }
}

// ---------------- flash attention, pipelined ----------------
// grid: 512 1-D blocks; decode: (b,kv) = id&7 (XCD-affine), then h-low, q-tile.
// block 256 = 4 waves; each wave owns TWO 16-row q-tiles (qi=0,1), QBLK=128.
// Swapped QK^T (S^T = mfma(K,Q)) so q is lane-local; online softmax = in-lane
// fold + 2 shfl_xor. K double-buffered, V single-buffered; counted s_waitcnt
// vmcnt(4) + raw s_barrier (no vmcnt(0) drain in the loop).
__global__ __launch_bounds__(256, 2) void k_flash(
    const unsigned short* __restrict__ packed,
    const unsigned short* __restrict__ vT,
    unsigned short* __restrict__ Y) {
  __shared__ unsigned short Ks[2][64 * 128];   // 32KB; also Q[128][128] staging
  __shared__ unsigned short Vs[128 * 64];      // 16KB
  __shared__ unsigned short Ps[4][2][16 * 68]; // per-wave P, stride 68
  __shared__ float Axc[4][2][16];
  int tid = threadIdx.x, lane = tid & 63, wid = tid >> 6;
  int row16 = lane & 15, kq = lane >> 4;
  int r3 = row16 & 7;                          // swizzle key for reads
  int g = blockIdx.x;
  int s8 = g & 7;                              // XCD-affine (b,kv)
  int b = s8 >> 2, kv = s8 & 3;
  int w = g >> 3;
  int h = kv * 4 + (w & 3);
  int qt = w >> 2;                             // 16 q-tiles x 128 rows
  size_t prow = (size_t)b * 2048;

  unsigned short* Q = &Ks[0][0];
  {  // stage Q [128][128] swizzled
    int rr = tid >> 4;
    int cc = ((tid & 15) ^ (rr & 7)) * 8;
    const unsigned short* qg = packed + (prow + qt * 128 + rr) * 3072 + h * 128 + cc;
#pragma unroll
    for (int i = 0; i < 8; i++)
      g2l16(qg + (size_t)i * 16 * 3072, &Q[i * 2048 + tid * 8]);
  }
  asm volatile("s_waitcnt vmcnt(0)" ::: "memory");
  __builtin_amdgcn_s_barrier();
  bf16x8 q[2][4];
#pragma unroll
  for (int qi = 0; qi < 2; qi++)
#pragma unroll
    for (int kc = 0; kc < 4; kc++)
      q[qi][kc] = *(const bf16x8*)&Q[(qi * 64 + wid * 16 + row16) * 128 + (((kc * 4 + kq) ^ r3) * 8)];
  asm volatile("s_waitcnt lgkmcnt(0)" ::: "memory");
  __builtin_amdgcn_sched_barrier(0);
  __builtin_amdgcn_s_barrier();   // Q consumed; Ks region reusable

  const unsigned short* kg0 = packed + prow * 3072 + 2048 + kv * 128;
  const unsigned short* vg0 = vT + (size_t)(b * 4 + kv) * 128 * 2048;
  int krr = tid >> 4;
  int kcc = ((tid & 15) ^ (krr & 7)) * 8;
  int vrr = tid >> 3;
  int vcc = ((tid & 7) ^ (vrr & 7)) * 8;

  auto stageK = [&](int t, int kbuf) {
    const unsigned short* kg = kg0 + (size_t)(t * 64 + krr) * 3072 + kcc;
#pragma unroll
    for (int i = 0; i < 4; i++)
      g2l16(kg + (size_t)i * 16 * 3072, &Ks[kbuf][i * 2048 + tid * 8]);
  };
  auto stageV = [&](int t) {
    const unsigned short* vg = vg0 + (size_t)vrr * 2048 + t * 64 + vcc;
#pragma unroll
    for (int i = 0; i < 4; i++)
      g2l16(vg + (size_t)i * 32 * 2048, &Vs[i * 2048 + tid * 8]);
  };

  stageK(0, 0);
  stageV(0);
  asm volatile("s_waitcnt vmcnt(4)" ::: "memory");   // K(0) done (V(0) in flight)
  __builtin_amdgcn_s_barrier();

  f32x4 o[2][8] = {};
  float mr[2] = {-1e30f, -1e30f}, lr[2] = {0.f, 0.f};
  const float sc2 = 0.08838834764831845f * 1.4426950408889634f;  // scale*log2e

  for (int t = 0; t < 32; t++) {
    int kb = t & 1;
    int tn = t < 31 ? t + 1 : 31;   // clamp keeps vmcnt counts uniform

    // ---- QK^T: S^T = K Q^T for both q-tiles ----
    f32x4 st[2][4];
#pragma unroll
    for (int qi = 0; qi < 2; qi++)
#pragma unroll
      for (int mk = 0; mk < 4; mk++) st[qi][mk] = f32x4{0.f, 0.f, 0.f, 0.f};
#pragma unroll
    for (int mk = 0; mk < 4; mk++) {
      bf16x8 bk[4];
#pragma unroll
      for (int kc = 0; kc < 4; kc++)
        bk[kc] = *(const bf16x8*)&Ks[kb][(mk * 16 + row16) * 128 + (((kc * 4 + kq) ^ r3) * 8)];
      __builtin_amdgcn_s_setprio(1);
#pragma unroll
      for (int kc = 0; kc < 4; kc++) {
        st[0][mk] = MFMA16(bk[kc], q[0][kc], st[0][mk]);
        st[1][mk] = MFMA16(bk[kc], q[1][kc], st[1][mk]);
      }
      __builtin_amdgcn_s_setprio(0);
    }

    // prefetch next K tile into the other buffer (waited at end of iter)
    stageK(tn, kb ^ 1);

    // ---- online softmax (log2 domain), q lane-local ----
#pragma unroll
    for (int qi = 0; qi < 2; qi++)
#pragma unroll
      for (int mk = 0; mk < 4; mk++) st[qi][mk] *= sc2;
    float pmax[2];
#pragma unroll
    for (int qi = 0; qi < 2; qi++) {
      float p = -1e30f;
#pragma unroll
      for (int mk = 0; mk < 4; mk++)
#pragma unroll
        for (int j = 0; j < 4; j++) p = fmaxf(p, st[qi][mk][j]);
      p = fmaxf(p, __shfl_xor(p, 16));
      p = fmaxf(p, __shfl_xor(p, 32));
      pmax[qi] = p;
    }
    if (!__all(pmax[0] <= mr[0] + 8.f && pmax[1] <= mr[1] + 8.f)) {
#pragma unroll
      for (int qi = 0; qi < 2; qi++) {
        float mn = fmaxf(mr[qi], pmax[qi]);
        float al = exp2f(mr[qi] - mn);
        mr[qi] = mn;
        lr[qi] *= al;
        if (lane < 16) Axc[wid][qi][row16] = al;
      }
#pragma unroll
      for (int qi = 0; qi < 2; qi++) {
        float alo[4];
#pragma unroll
        for (int j = 0; j < 4; j++) alo[j] = Axc[wid][qi][kq * 4 + j];
#pragma unroll
        for (int np = 0; np < 8; np++)
#pragma unroll
          for (int j = 0; j < 4; j++) o[qi][np][j] *= alo[j];
      }
    }
#pragma unroll
    for (int qi = 0; qi < 2; qi++) {
      float rs = 0.f;
#pragma unroll
      for (int mk = 0; mk < 4; mk++)
#pragma unroll
        for (int j = 0; j < 4; j++) {
          st[qi][mk][j] = exp2f(st[qi][mk][j] - mr[qi]);
          rs += st[qi][mk][j];
        }
      rs += __shfl_xor(rs, 16);
      rs += __shfl_xor(rs, 32);
      lr[qi] += rs;
    }

    // P -> LDS (per-wave, stride 68), then read back as PV A-frags
    bf16x8 pf[2][2];
#pragma unroll
    for (int qi = 0; qi < 2; qi++) {
#pragma unroll
      for (int mk = 0; mk < 4; mk++) {
        ushort4 pw;
        pw.x = f2bf(st[qi][mk][0]); pw.y = f2bf(st[qi][mk][1]);
        pw.z = f2bf(st[qi][mk][2]); pw.w = f2bf(st[qi][mk][3]);
        *(ushort4*)&Ps[wid][qi][row16 * 68 + mk * 16 + kq * 4] = pw;
      }
#pragma unroll
      for (int k2 = 0; k2 < 2; k2++)
        pf[qi][k2] = *(const bf16x8*)&Ps[wid][qi][row16 * 68 + k2 * 32 + kq * 8];
    }

    // V(t) ready? (outstanding: V(t) then K(t+1) -> wait to 4 = V done)
    asm volatile("s_waitcnt vmcnt(4)" ::: "memory");
    __builtin_amdgcn_s_barrier();

    // ---- O += P V ----
#pragma unroll
    for (int np = 0; np < 8; np++) {
      int vrow = np * 16 + row16;
      bf16x8 bv0 = *(const bf16x8*)&Vs[vrow * 64 + ((kq ^ r3) * 8)];
      bf16x8 bv1 = *(const bf16x8*)&Vs[vrow * 64 + (((4 + kq) ^ r3) * 8)];
      __builtin_amdgcn_s_setprio(1);
      o[0][np] = MFMA16(pf[0][0], bv0, o[0][np]);
      o[0][np] = MFMA16(pf[0][1], bv1, o[0][np]);
      o[1][np] = MFMA16(pf[1][0], bv0, o[1][np]);
      o[1][np] = MFMA16(pf[1][1], bv1, o[1][np]);
      __builtin_amdgcn_s_setprio(0);
    }

    __builtin_amdgcn_s_barrier();   // all waves done reading Vs
    stageV(tn);                     // prefetch next V (consumed after next QK+softmax)
    asm volatile("s_waitcnt vmcnt(4)" ::: "memory");  // K(t+1) done (V(t+1) in flight)
    __builtin_amdgcn_s_barrier();
  }
  asm volatile("s_waitcnt vmcnt(0)" ::: "memory");    // drain dangling prefetches

  // epilogue: redistribute l (softmax layout q=row16 -> O layout q=kq*4+j)
#pragma unroll
  for (int qi = 0; qi < 2; qi++)
    if (lane < 16) Axc[wid][qi][row16] = lr[qi];
#pragma unroll
  for (int qi = 0; qi < 2; qi++)
#pragma unroll
    for (int j = 0; j < 4; j++) {
      float inv = 1.f / Axc[wid][qi][kq * 4 + j];
      size_t orow = prow + (size_t)qt * 128 + qi * 64 + wid * 16 + kq * 4 + j;
#pragma unroll
      for (int np = 0; np < 8; np++)
        Y[orow * 2048 + h * 128 + np * 16 + row16] = f2bf(o[qi][np][j] * inv);
    }
}

extern "C" void kernel_launch(void* const* d_in, const int* in_sizes, int n_in,
                              void* d_out, int out_size, void* d_ws, size_t ws_size,
                              hipStream_t stream) {
  const float* x     = (const float*)d_in[0];
  const float* in_w  = (const float*)d_in[1];
  const float* in_b  = (const float*)d_in[2];
  const float* out_w = (const float*)d_in[3];
  const float* out_b = (const float*)d_in[4];
  float* out = (float*)d_out;

  unsigned short* xb     = (unsigned short*)d_ws;            // 8388608
  unsigned short* wb     = xb + 8388608;                     // 6291456
  unsigned short* owb    = wb + 6291456;                     // 4194304
  unsigned short* packed = owb + 4194304;                    // 12582912
  unsigned short* vt     = packed + 12582912;                // 2097152
  unsigned short* y      = vt + 2097152;                     // 8388608

  k_cvt<<<dim3(1024), dim3(256), 0, stream>>>(x, xb, 8388608 / 4);
  k_cvt<<<dim3(1024), dim3(256), 0, stream>>>(in_w, wb, 6291456 / 4);
  k_cvt<<<dim3(1024), dim3(256), 0, stream>>>(out_w, owb, 4194304 / 4);

  k_gemm<true><<<dim3(24, 32), dim3(256), 0, stream>>>(xb, wb, in_b, packed, 4096, 3072, 2048);
  k_vt<<<dim3(32, 8), dim3(256), 0, stream>>>(packed, vt);
  k_flash<<<dim3(512), dim3(256), 0, stream>>>(packed, vt, y);
  k_gemm<false><<<dim3(16, 32), dim3(256), 0, stream>>>(y, owb, out_b, out, 4096, 2048, 2048);
}

// Round 5
// 229.955 us; speedup vs baseline: 1.4436x; 1.0299x over previous
//
#include <hip/hip_runtime.h>
#include <hip/hip_bf16.h>
#include <stdint.h>

#define DEV __device__ __forceinline__

typedef __attribute__((ext_vector_type(8))) short bf16x8;
typedef __attribute__((ext_vector_type(4))) float f32x4;

DEV unsigned short f2bf(float f) {
  unsigned u = __builtin_bit_cast(unsigned, f);
  unsigned r = u + 0x7FFF + ((u >> 16) & 1);   // RNE
  return (unsigned short)(r >> 16);
}

// native bf16 convert (lowers to v_cvt_pk_bf16_f32) — hot-loop use
DEV unsigned short f2bfh(float f) {
  __bf16 h = (__bf16)f;
  return __builtin_bit_cast(unsigned short, h);
}

typedef __attribute__((address_space(1))) void gvoid;
typedef __attribute__((address_space(3))) void lvoid;

DEV void g2l16(const void* g, void* l) {
  __builtin_amdgcn_global_load_lds((gvoid*)g, (lvoid*)l, 16, 0, 0);
}

#define MFMA16(a, b, c) __builtin_amdgcn_mfma_f32_16x16x32_bf16(a, b, c, 0, 0, 0)

// ---------------- fp32 -> bf16 convert, 3 arrays fused ----------------
__global__ void k_cvt3(const float* __restrict__ x, unsigned short* __restrict__ xo, int nx4,
                       const float* __restrict__ w, unsigned short* __restrict__ wo, int nw4,
                       const float* __restrict__ v, unsigned short* __restrict__ vo, int nv4) {
  int i = blockIdx.x * blockDim.x + threadIdx.x;
  int stride = gridDim.x * blockDim.x;
  int tot = nx4 + nw4 + nv4;
  for (; i < tot; i += stride) {
    const float* src; unsigned short* dst; int j = i;
    if (j < nx4) { src = x; dst = xo; }
    else if ((j -= nx4) < nw4) { src = w; dst = wo; }
    else { j -= nw4; src = v; dst = vo; }
    float4 val = reinterpret_cast<const float4*>(src)[j];
    ushort4 o;
    o.x = f2bf(val.x); o.y = f2bf(val.y); o.z = f2bf(val.z); o.w = f2bf(val.w);
    reinterpret_cast<ushort4*>(dst)[j] = o;
  }
}

// ---------------- 128x128 tile bf16 GEMM, B given as B^T [N][K], +bias ----------------
template<bool BF16OUT>
__global__ __launch_bounds__(256, 2) void k_gemm(
    const unsigned short* __restrict__ A, const unsigned short* __restrict__ B,
    const float* __restrict__ bias, void* __restrict__ C,
    int M, int N, int K) {
  __shared__ unsigned short As[128 * 32];
  __shared__ unsigned short Bs[128 * 32];
  int tid = threadIdx.x;
  int lane = tid & 63, wid = tid >> 6;
  int bm = blockIdx.y * 128, bn = blockIdx.x * 128;
  int wm = (wid >> 1) * 64, wn = (wid & 1) * 64;
  int row16 = lane & 15, kq = lane >> 4;
  f32x4 acc[4][4] = {};
  int r = tid >> 2, c = (tid & 3) * 8;
  const unsigned short* Ag = A + (size_t)(bm + r) * K + c;
  const unsigned short* Bg = B + (size_t)(bn + r) * K + c;
  for (int k0 = 0; k0 < K; k0 += 32) {
    g2l16(Ag + k0, &As[tid * 8]);
    g2l16(Ag + (size_t)64 * K + k0, &As[2048 + tid * 8]);
    g2l16(Bg + k0, &Bs[tid * 8]);
    g2l16(Bg + (size_t)64 * K + k0, &Bs[2048 + tid * 8]);
    __syncthreads();
    bf16x8 a[4], b[4];
#pragma unroll
    for (int m = 0; m < 4; m++) a[m] = *(const bf16x8*)&As[(wm + m * 16 + row16) * 32 + kq * 8];
#pragma unroll
    for (int n = 0; n < 4; n++) b[n] = *(const bf16x8*)&Bs[(wn + n * 16 + row16) * 32 + kq * 8];
    __builtin_amdgcn_s_setprio(1);
#pragma unroll
    for (int m = 0; m < 4; m++)
#pragma unroll
      for (int n = 0; n < 4; n++)
        acc[m][n] = MFMA16(a[m], b[n], acc[m][n]);
    __builtin_amdgcn_s_setprio(0);
    __syncthreads();
  }
#pragma unroll
  for (int n = 0; n < 4; n++) {
    int col = bn + wn + n * 16 + row16;
    float bv = bias[col];
#pragma unroll
    for (int m = 0; m < 4; m++) {
      int rw = bm + wm + m * 16 + kq * 4;
#pragma unroll
      for (int j = 0; j < 4; j++) {
        float v = acc[m][n][j] + bv;
        if (BF16OUT) ((unsigned short*)C)[(size_t)(rw + j) * N + col] = f2bf(v);
        else         ((float*)C)[(size_t)(rw + j) * N + col] = v;
      }
    }
  }
}

// ---------------- V transpose: packed[b,t,2560+kv*128+d] -> vT[(b*4+kv)*128+d][t] ----------------
__global__ void k_vt(const unsigned short* __restrict__ packed, unsigned short* __restrict__ vT) {
  __shared__ unsigned short tile[64][136];
  int g = blockIdx.y;            // b*4+kv
  int b = g >> 2, kv = g & 3;
  int t0 = blockIdx.x * 64;
  int tid = threadIdx.x;
#pragma unroll
  for (int i = 0; i < 4; i++) {
    int tl = i * 16 + (tid >> 4);
    int d0 = (tid & 15) * 8;
    bf16x8 v = *(const bf16x8*)&packed[(size_t)(b * 2048 + t0 + tl) * 3072 + 2560 + kv * 128 + d0];
    *(bf16x8*)&tile[tl][d0] = v;
  }
  __syncthreads();
  int d = tid >> 1, ts = (tid & 1) * 32;
  size_t obase = (size_t)(g * 128 + d) * 2048 + t0 + ts;
#pragma unroll
  for (int j = 0; j < 4; j++) {
    bf16x8 o;
#pragma unroll
    for (int e = 0; e < 8; e++) o[e] = (short)tile[ts + j * 8 + e][d];
    *(bf16x8*)&vT[obase + j * 8] = o;
  }
}

// ---------------- flash attention, pipelined ----------------
// grid: 512 1-D blocks; decode: (b,kv) = id&7 (XCD-affine), then h-low, q-tile.
// block 256 = 4 waves; each wave owns TWO 16-row q-tiles (qi=0,1), QBLK=128.
// Swapped QK^T (S^T = mfma(K,Q)) so q is lane-local; online softmax = in-lane
// tree fold + 2 shfl_xor; scale folded into exp via fma; native bf16 cvt.
// K double-buffered, V single-buffered; counted s_waitcnt vmcnt(4) + raw
// s_barrier (no vmcnt(0) drain in the loop).
__global__ __launch_bounds__(256, 2) void k_flash(
    const unsigned short* __restrict__ packed,
    const unsigned short* __restrict__ vT,
    unsigned short* __restrict__ Y) {
  __shared__ unsigned short Ks[2][64 * 128];   // 32KB; also Q[128][128] staging
  __shared__ unsigned short Vs[128 * 64];      // 16KB
  __shared__ unsigned short Ps[4][2][16 * 68]; // per-wave P, stride 68
  __shared__ float Axc[4][2][16];
  int tid = threadIdx.x, lane = tid & 63, wid = tid >> 6;
  int row16 = lane & 15, kq = lane >> 4;
  int r3 = row16 & 7;                          // swizzle key for reads
  int g = blockIdx.x;
  int s8 = g & 7;                              // XCD-affine (b,kv)
  int b = s8 >> 2, kv = s8 & 3;
  int w = g >> 3;
  int h = kv * 4 + (w & 3);
  int qt = w >> 2;                             // 16 q-tiles x 128 rows
  size_t prow = (size_t)b * 2048;

  unsigned short* Q = &Ks[0][0];
  {  // stage Q [128][128] swizzled
    int rr = tid >> 4;
    int cc = ((tid & 15) ^ (rr & 7)) * 8;
    const unsigned short* qg = packed + (prow + qt * 128 + rr) * 3072 + h * 128 + cc;
#pragma unroll
    for (int i = 0; i < 8; i++)
      g2l16(qg + (size_t)i * 16 * 3072, &Q[i * 2048 + tid * 8]);
  }
  asm volatile("s_waitcnt vmcnt(0)" ::: "memory");
  __builtin_amdgcn_s_barrier();
  bf16x8 q[2][4];
#pragma unroll
  for (int qi = 0; qi < 2; qi++)
#pragma unroll
    for (int kc = 0; kc < 4; kc++)
      q[qi][kc] = *(const bf16x8*)&Q[(qi * 64 + wid * 16 + row16) * 128 + (((kc * 4 + kq) ^ r3) * 8)];
  asm volatile("s_waitcnt lgkmcnt(0)" ::: "memory");
  __builtin_amdgcn_sched_barrier(0);
  __builtin_amdgcn_s_barrier();   // Q consumed; Ks region reusable

  const unsigned short* kg0 = packed + prow * 3072 + 2048 + kv * 128;
  const unsigned short* vg0 = vT + (size_t)(b * 4 + kv) * 128 * 2048;
  int krr = tid >> 4;
  int kcc = ((tid & 15) ^ (krr & 7)) * 8;
  int vrr = tid >> 3;
  int vcc = ((tid & 7) ^ (vrr & 7)) * 8;

  auto stageK = [&](int t, int kbuf) {
    const unsigned short* kg = kg0 + (size_t)(t * 64 + krr) * 3072 + kcc;
#pragma unroll
    for (int i = 0; i < 4; i++)
      g2l16(kg + (size_t)i * 16 * 3072, &Ks[kbuf][i * 2048 + tid * 8]);
  };
  auto stageV = [&](int t) {
    const unsigned short* vg = vg0 + (size_t)vrr * 2048 + t * 64 + vcc;
#pragma unroll
    for (int i = 0; i < 4; i++)
      g2l16(vg + (size_t)i * 32 * 2048, &Vs[i * 2048 + tid * 8]);
  };

  stageK(0, 0);
  stageV(0);
  asm volatile("s_waitcnt vmcnt(4)" ::: "memory");   // K(0) done (V(0) in flight)
  __builtin_amdgcn_s_barrier();

  f32x4 o[2][8] = {};
  float mr[2] = {-1e30f, -1e30f}, lr[2] = {0.f, 0.f};
  const float sc2 = 0.08838834764831845f * 1.4426950408889634f;  // scale*log2e

  for (int t = 0; t < 32; t++) {
    int kb = t & 1;
    int tn = t < 31 ? t + 1 : 31;   // clamp keeps vmcnt counts uniform

    // ---- QK^T: S^T = K Q^T for both q-tiles ----
    f32x4 st[2][4];
#pragma unroll
    for (int qi = 0; qi < 2; qi++)
#pragma unroll
      for (int mk = 0; mk < 4; mk++) st[qi][mk] = f32x4{0.f, 0.f, 0.f, 0.f};
#pragma unroll
    for (int mk = 0; mk < 4; mk++) {
      bf16x8 bk[4];
#pragma unroll
      for (int kc = 0; kc < 4; kc++)
        bk[kc] = *(const bf16x8*)&Ks[kb][(mk * 16 + row16) * 128 + (((kc * 4 + kq) ^ r3) * 8)];
      __builtin_amdgcn_s_setprio(1);
#pragma unroll
      for (int kc = 0; kc < 4; kc++) {
        st[0][mk] = MFMA16(bk[kc], q[0][kc], st[0][mk]);
        st[1][mk] = MFMA16(bk[kc], q[1][kc], st[1][mk]);
      }
      __builtin_amdgcn_s_setprio(0);
    }

    // prefetch next K tile into the other buffer (waited at end of iter)
    stageK(tn, kb ^ 1);

    // ---- online softmax (log2 domain, scale folded into fma), q lane-local ----
    float pmax[2];
#pragma unroll
    for (int qi = 0; qi < 2; qi++) {
      float a0 = fmaxf(fmaxf(st[qi][0][0], st[qi][0][1]), fmaxf(st[qi][0][2], st[qi][0][3]));
      float a1 = fmaxf(fmaxf(st[qi][1][0], st[qi][1][1]), fmaxf(st[qi][1][2], st[qi][1][3]));
      float a2 = fmaxf(fmaxf(st[qi][2][0], st[qi][2][1]), fmaxf(st[qi][2][2], st[qi][2][3]));
      float a3 = fmaxf(fmaxf(st[qi][3][0], st[qi][3][1]), fmaxf(st[qi][3][2], st[qi][3][3]));
      float p = fmaxf(fmaxf(a0, a1), fmaxf(a2, a3));
      p = fmaxf(p, __shfl_xor(p, 16));
      p = fmaxf(p, __shfl_xor(p, 32));
      pmax[qi] = p * sc2;          // into scaled-log2 domain
    }
    if (!__all(pmax[0] <= mr[0] + 8.f && pmax[1] <= mr[1] + 8.f)) {
#pragma unroll
      for (int qi = 0; qi < 2; qi++) {
        float mn = fmaxf(mr[qi], pmax[qi]);
        float al = exp2f(mr[qi] - mn);
        mr[qi] = mn;
        lr[qi] *= al;
        if (lane < 16) Axc[wid][qi][row16] = al;
      }
#pragma unroll
      for (int qi = 0; qi < 2; qi++) {
        float alo[4];
#pragma unroll
        for (int j = 0; j < 4; j++) alo[j] = Axc[wid][qi][kq * 4 + j];
#pragma unroll
        for (int np = 0; np < 8; np++)
#pragma unroll
          for (int j = 0; j < 4; j++) o[qi][np][j] *= alo[j];
      }
    }
#pragma unroll
    for (int qi = 0; qi < 2; qi++) {
      float nm = -mr[qi];
#pragma unroll
      for (int mk = 0; mk < 4; mk++)
#pragma unroll
        for (int j = 0; j < 4; j++)
          st[qi][mk][j] = exp2f(fmaf(st[qi][mk][j], sc2, nm));
      float s0 = (st[qi][0][0] + st[qi][0][1]) + (st[qi][0][2] + st[qi][0][3]);
      float s1 = (st[qi][1][0] + st[qi][1][1]) + (st[qi][1][2] + st[qi][1][3]);
      float s2 = (st[qi][2][0] + st[qi][2][1]) + (st[qi][2][2] + st[qi][2][3]);
      float s3 = (st[qi][3][0] + st[qi][3][1]) + (st[qi][3][2] + st[qi][3][3]);
      float rs = (s0 + s1) + (s2 + s3);
      rs += __shfl_xor(rs, 16);
      rs += __shfl_xor(rs, 32);
      lr[qi] += rs;
    }

    // P -> LDS (per-wave, stride 68), then read back as PV A-frags
    bf16x8 pf[2][2];
#pragma unroll
    for (int qi = 0; qi < 2; qi++) {
#pragma unroll
      for (int mk = 0; mk < 4; mk++) {
        ushort4 pw;
        pw.x = f2bfh(st[qi][mk][0]); pw.y = f2bfh(st[qi][mk][1]);
        pw.z = f2bfh(st[qi][mk][2]); pw.w = f2bfh(st[qi][mk][3]);
        *(ushort4*)&Ps[wid][qi][row16 * 68 + mk * 16 + kq * 4] = pw;
      }
#pragma unroll
      for (int k2 = 0; k2 < 2; k2++)
        pf[qi][k2] = *(const bf16x8*)&Ps[wid][qi][row16 * 68 + k2 * 32 + kq * 8];
    }

    // V(t) ready? (outstanding: V(t) then K(t+1) -> wait to 4 = V done)
    asm volatile("s_waitcnt vmcnt(4)" ::: "memory");
    __builtin_amdgcn_s_barrier();

    // ---- O += P V ----
#pragma unroll
    for (int np = 0; np < 8; np++) {
      int vrow = np * 16 + row16;
      bf16x8 bv0 = *(const bf16x8*)&Vs[vrow * 64 + ((kq ^ r3) * 8)];
      bf16x8 bv1 = *(const bf16x8*)&Vs[vrow * 64 + (((4 + kq) ^ r3) * 8)];
      __builtin_amdgcn_s_setprio(1);
      o[0][np] = MFMA16(pf[0][0], bv0, o[0][np]);
      o[0][np] = MFMA16(pf[0][1], bv1, o[0][np]);
      o[1][np] = MFMA16(pf[1][0], bv0, o[1][np]);
      o[1][np] = MFMA16(pf[1][1], bv1, o[1][np]);
      __builtin_amdgcn_s_setprio(0);
    }

    __builtin_amdgcn_s_barrier();   // all waves done reading Vs
    stageV(tn);                     // prefetch next V (consumed after next QK+softmax)
    asm volatile("s_waitcnt vmcnt(4)" ::: "memory");  // K(t+1) done (V(t+1) in flight)
    __builtin_amdgcn_s_barrier();
  }
  asm volatile("s_waitcnt vmcnt(0)" ::: "memory");    // drain dangling prefetches

  // epilogue: redistribute l (softmax layout q=row16 -> O layout q=kq*4+j)
#pragma unroll
  for (int qi = 0; qi < 2; qi++)
    if (lane < 16) Axc[wid][qi][row16] = lr[qi];
#pragma unroll
  for (int qi = 0; qi < 2; qi++)
#pragma unroll
    for (int j = 0; j < 4; j++) {
      float inv = 1.f / Axc[wid][qi][kq * 4 + j];
      size_t orow = prow + (size_t)qt * 128 + qi * 64 + wid * 16 + kq * 4 + j;
#pragma unroll
      for (int np = 0; np < 8; np++)
        Y[orow * 2048 + h * 128 + np * 16 + row16] = f2bfh(o[qi][np][j] * inv);
    }
}

extern "C" void kernel_launch(void* const* d_in, const int* in_sizes, int n_in,
                              void* d_out, int out_size, void* d_ws, size_t ws_size,
                              hipStream_t stream) {
  const float* x     = (const float*)d_in[0];
  const float* in_w  = (const float*)d_in[1];
  const float* in_b  = (const float*)d_in[2];
  const float* out_w = (const float*)d_in[3];
  const float* out_b = (const float*)d_in[4];
  float* out = (float*)d_out;

  unsigned short* xb     = (unsigned short*)d_ws;            // 8388608
  unsigned short* wb     = xb + 8388608;                     // 6291456
  unsigned short* owb    = wb + 6291456;                     // 4194304
  unsigned short* packed = owb + 4194304;                    // 12582912
  unsigned short* vt     = packed + 12582912;                // 2097152
  unsigned short* y      = vt + 2097152;                     // 8388608

  k_cvt3<<<dim3(2048), dim3(256), 0, stream>>>(x, xb, 8388608 / 4,
                                               in_w, wb, 6291456 / 4,
                                               out_w, owb, 4194304 / 4);

  k_gemm<true><<<dim3(24, 32), dim3(256), 0, stream>>>(xb, wb, in_b, packed, 4096, 3072, 2048);
  k_vt<<<dim3(32, 8), dim3(256), 0, stream>>>(packed, vt);
  k_flash<<<dim3(512), dim3(256), 0, stream>>>(packed, vt, y);
  k_gemm<false><<<dim3(16, 32), dim3(256), 0, stream>>>(y, owb, out_b, out, 4096, 2048, 2048);
}

// Round 6
// 226.339 us; speedup vs baseline: 1.4666x; 1.0160x over previous
//
#include <hip/hip_runtime.h>
#include <hip/hip_bf16.h>
#include <stdint.h>

#define DEV __device__ __forceinline__

typedef __attribute__((ext_vector_type(8))) short bf16x8;
typedef __attribute__((ext_vector_type(4))) float f32x4;

DEV unsigned short f2bf(float f) {
  unsigned u = __builtin_bit_cast(unsigned, f);
  unsigned r = u + 0x7FFF + ((u >> 16) & 1);   // RNE
  return (unsigned short)(r >> 16);
}

// native bf16 convert (compiler packs pairs into v_cvt_pk_bf16_f32)
DEV unsigned short f2bfh(float f) {
  __bf16 h = (__bf16)f;
  return __builtin_bit_cast(unsigned short, h);
}

typedef __attribute__((address_space(1))) void gvoid;
typedef __attribute__((address_space(3))) void lvoid;

DEV void g2l16(const void* g, void* l) {
  __builtin_amdgcn_global_load_lds((gvoid*)g, (lvoid*)l, 16, 0, 0);
}

#define MFMA16(a, b, c) __builtin_amdgcn_mfma_f32_16x16x32_bf16(a, b, c, 0, 0, 0)

// ---------------- fp32 -> bf16 convert, 3 arrays fused ----------------
__global__ void k_cvt3(const float* __restrict__ x, unsigned short* __restrict__ xo, int nx4,
                       const float* __restrict__ w, unsigned short* __restrict__ wo, int nw4,
                       const float* __restrict__ v, unsigned short* __restrict__ vo, int nv4) {
  int i = blockIdx.x * blockDim.x + threadIdx.x;
  int stride = gridDim.x * blockDim.x;
  int tot = nx4 + nw4 + nv4;
  for (; i < tot; i += stride) {
    const float* src; unsigned short* dst; int j = i;
    if (j < nx4) { src = x; dst = xo; }
    else if ((j -= nx4) < nw4) { src = w; dst = wo; }
    else { j -= nw4; src = v; dst = vo; }
    float4 val = reinterpret_cast<const float4*>(src)[j];
    ushort4 o;
    o.x = f2bf(val.x); o.y = f2bf(val.y); o.z = f2bf(val.z); o.w = f2bf(val.w);
    reinterpret_cast<ushort4*>(dst)[j] = o;
  }
}

// ---------------- 128x128 tile bf16 GEMM, B given as B^T [N][K], +bias ----------------
template<bool BF16OUT>
__global__ __launch_bounds__(256, 2) void k_gemm(
    const unsigned short* __restrict__ A, const unsigned short* __restrict__ B,
    const float* __restrict__ bias, void* __restrict__ C,
    int M, int N, int K) {
  __shared__ unsigned short As[128 * 32];
  __shared__ unsigned short Bs[128 * 32];
  int tid = threadIdx.x;
  int lane = tid & 63, wid = tid >> 6;
  int bm = blockIdx.y * 128, bn = blockIdx.x * 128;
  int wm = (wid >> 1) * 64, wn = (wid & 1) * 64;
  int row16 = lane & 15, kq = lane >> 4;
  f32x4 acc[4][4] = {};
  int r = tid >> 2, c = (tid & 3) * 8;
  const unsigned short* Ag = A + (size_t)(bm + r) * K + c;
  const unsigned short* Bg = B + (size_t)(bn + r) * K + c;
  for (int k0 = 0; k0 < K; k0 += 32) {
    g2l16(Ag + k0, &As[tid * 8]);
    g2l16(Ag + (size_t)64 * K + k0, &As[2048 + tid * 8]);
    g2l16(Bg + k0, &Bs[tid * 8]);
    g2l16(Bg + (size_t)64 * K + k0, &Bs[2048 + tid * 8]);
    __syncthreads();
    bf16x8 a[4], b[4];
#pragma unroll
    for (int m = 0; m < 4; m++) a[m] = *(const bf16x8*)&As[(wm + m * 16 + row16) * 32 + kq * 8];
#pragma unroll
    for (int n = 0; n < 4; n++) b[n] = *(const bf16x8*)&Bs[(wn + n * 16 + row16) * 32 + kq * 8];
    __builtin_amdgcn_s_setprio(1);
#pragma unroll
    for (int m = 0; m < 4; m++)
#pragma unroll
      for (int n = 0; n < 4; n++)
        acc[m][n] = MFMA16(a[m], b[n], acc[m][n]);
    __builtin_amdgcn_s_setprio(0);
    __syncthreads();
  }
#pragma unroll
  for (int n = 0; n < 4; n++) {
    int col = bn + wn + n * 16 + row16;
    float bv = bias[col];
#pragma unroll
    for (int m = 0; m < 4; m++) {
      int rw = bm + wm + m * 16 + kq * 4;
#pragma unroll
      for (int j = 0; j < 4; j++) {
        float v = acc[m][n][j] + bv;
        if (BF16OUT) ((unsigned short*)C)[(size_t)(rw + j) * N + col] = f2bf(v);
        else         ((float*)C)[(size_t)(rw + j) * N + col] = v;
      }
    }
  }
}

// ---------------- V transpose: packed[b,t,2560+kv*128+d] -> vT[(b*4+kv)*128+d][t] ----------------
__global__ void k_vt(const unsigned short* __restrict__ packed, unsigned short* __restrict__ vT) {
  __shared__ unsigned short tile[64][136];
  int g = blockIdx.y;            // b*4+kv
  int b = g >> 2, kv = g & 3;
  int t0 = blockIdx.x * 64;
  int tid = threadIdx.x;
#pragma unroll
  for (int i = 0; i < 4; i++) {
    int tl = i * 16 + (tid >> 4);
    int d0 = (tid & 15) * 8;
    bf16x8 v = *(const bf16x8*)&packed[(size_t)(b * 2048 + t0 + tl) * 3072 + 2560 + kv * 128 + d0];
    *(bf16x8*)&tile[tl][d0] = v;
  }
  __syncthreads();
  int d = tid >> 1, ts = (tid & 1) * 32;
  size_t obase = (size_t)(g * 128 + d) * 2048 + t0 + ts;
#pragma unroll
  for (int j = 0; j < 4; j++) {
    bf16x8 o;
#pragma unroll
    for (int e = 0; e < 8; e++) o[e] = (short)tile[ts + j * 8 + e][d];
    *(bf16x8*)&vT[obase + j * 8] = o;
  }
}

// ---------------- flash attention, pipelined, 8 waves ----------------
// grid: 512 1-D blocks; decode: (b,kv) = id&7 (XCD-affine), then h-low, q-tile.
// block 512 = 8 waves; each wave owns ONE 16-row q-tile; QBLK=128.
// 16 waves/CU = 4/SIMD (TLP for stall fill). Swapped QK^T (S^T = mfma(K,Q)):
// q lane-local; max = in-lane fold + 2 shfl; row-sum l = ones-MFMA (lands in
// O layout). K double-buffered, V single-buffered; counted s_waitcnt vmcnt(2)
// + raw s_barrier (no vmcnt(0) drain in the loop).
__global__ __launch_bounds__(512, 4) void k_flash(
    const unsigned short* __restrict__ packed,
    const unsigned short* __restrict__ vT,
    unsigned short* __restrict__ Y) {
  __shared__ unsigned short Ks[2][64 * 128];   // 32KB; Q[128][128] staging spans both
  __shared__ unsigned short Vs[128 * 64];      // 16KB
  __shared__ unsigned short Ps[8][16 * 72];    // per-wave P, stride 72 (2-way = free)
  __shared__ float Axc[8][16];
  int tid = threadIdx.x, lane = tid & 63, wid = tid >> 6;
  int row16 = lane & 15, kq = lane >> 4;
  int r3 = row16 & 7;                          // swizzle key for reads
  int g = blockIdx.x;
  int s8 = g & 7;                              // XCD-affine (b,kv)
  int b = s8 >> 2, kv = s8 & 3;
  int w = g >> 3;
  int h = kv * 4 + (w & 3);
  int qt = w >> 2;                             // 16 q-tiles x 128 rows
  size_t prow = (size_t)b * 2048;

  unsigned short* Q = &Ks[0][0];
  {  // stage Q [128][128] swizzled (4 passes x 32 rows, 512 threads)
    int rr = tid >> 4;
    int cc = ((tid & 15) ^ (rr & 7)) * 8;
    const unsigned short* qg = packed + (prow + qt * 128 + rr) * 3072 + h * 128 + cc;
#pragma unroll
    for (int i = 0; i < 4; i++)
      g2l16(qg + (size_t)i * 32 * 3072, &Q[i * 4096 + tid * 8]);
  }
  asm volatile("s_waitcnt vmcnt(0)" ::: "memory");
  __builtin_amdgcn_s_barrier();
  bf16x8 q[4];
#pragma unroll
  for (int kc = 0; kc < 4; kc++)
    q[kc] = *(const bf16x8*)&Q[(wid * 16 + row16) * 128 + (((kc * 4 + kq) ^ r3) * 8)];
  asm volatile("s_waitcnt lgkmcnt(0)" ::: "memory");
  __builtin_amdgcn_sched_barrier(0);
  __builtin_amdgcn_s_barrier();   // Q consumed; Ks region reusable

  const unsigned short* kg0 = packed + prow * 3072 + 2048 + kv * 128;
  const unsigned short* vg0 = vT + (size_t)(b * 4 + kv) * 128 * 2048;
  int krr = tid >> 4;
  int kcc = ((tid & 15) ^ (krr & 7)) * 8;
  int vrr = tid >> 3;
  int vcc = ((tid & 7) ^ (vrr & 7)) * 8;

  auto stageK = [&](int t, int kbuf) {     // 2 passes x 32 rows
    const unsigned short* kg = kg0 + (size_t)(t * 64 + krr) * 3072 + kcc;
#pragma unroll
    for (int i = 0; i < 2; i++)
      g2l16(kg + (size_t)i * 32 * 3072, &Ks[kbuf][i * 4096 + tid * 8]);
  };
  auto stageV = [&](int t) {               // 2 passes x 64 rows
    const unsigned short* vg = vg0 + (size_t)vrr * 2048 + t * 64 + vcc;
#pragma unroll
    for (int i = 0; i < 2; i++)
      g2l16(vg + (size_t)i * 64 * 2048, &Vs[i * 4096 + tid * 8]);
  };

  stageK(0, 0);
  stageV(0);
  asm volatile("s_waitcnt vmcnt(2)" ::: "memory");   // K(0) done (V(0) in flight)
  __builtin_amdgcn_s_barrier();

  f32x4 o[8] = {};
  f32x4 ls = {};                 // row sums via ones-MFMA, O layout
  float mr = -1e30f;
  const float sc2 = 0.08838834764831845f * 1.4426950408889634f;  // scale*log2e
  bf16x8 ones;
#pragma unroll
  for (int e = 0; e < 8; e++) ones[e] = (short)0x3F80;   // bf16 1.0

  for (int t = 0; t < 32; t++) {
    int kb = t & 1;
    int tn = t < 31 ? t + 1 : 31;   // clamp keeps vmcnt counts uniform

    // ---- QK^T: S^T = K Q^T ----
    f32x4 st[4];
#pragma unroll
    for (int mk = 0; mk < 4; mk++) {
      st[mk] = f32x4{0.f, 0.f, 0.f, 0.f};
      bf16x8 bk[4];
#pragma unroll
      for (int kc = 0; kc < 4; kc++)
        bk[kc] = *(const bf16x8*)&Ks[kb][(mk * 16 + row16) * 128 + (((kc * 4 + kq) ^ r3) * 8)];
      __builtin_amdgcn_s_setprio(1);
#pragma unroll
      for (int kc = 0; kc < 4; kc++)
        st[mk] = MFMA16(bk[kc], q[kc], st[mk]);
      __builtin_amdgcn_s_setprio(0);
    }

    // prefetch next K tile into the other buffer (waited at end of iter)
    stageK(tn, kb ^ 1);

    // ---- online softmax (log2 domain, scale folded into fma), q lane-local ----
    float a0 = fmaxf(fmaxf(st[0][0], st[0][1]), fmaxf(st[0][2], st[0][3]));
    float a1 = fmaxf(fmaxf(st[1][0], st[1][1]), fmaxf(st[1][2], st[1][3]));
    float a2 = fmaxf(fmaxf(st[2][0], st[2][1]), fmaxf(st[2][2], st[2][3]));
    float a3 = fmaxf(fmaxf(st[3][0], st[3][1]), fmaxf(st[3][2], st[3][3]));
    float p = fmaxf(fmaxf(a0, a1), fmaxf(a2, a3));
    p = fmaxf(p, __shfl_xor(p, 16));
    p = fmaxf(p, __shfl_xor(p, 32));
    p *= sc2;                     // scaled-log2 domain
    if (!__all(p <= mr + 8.f)) {  // defer-max: skip rescale when growth small
      float mn = fmaxf(mr, p);
      float al = exp2f(mr - mn);
      mr = mn;
      if (lane < 16) Axc[wid][row16] = al;
      float alo[4];
#pragma unroll
      for (int j = 0; j < 4; j++) alo[j] = Axc[wid][kq * 4 + j];
#pragma unroll
      for (int np = 0; np < 8; np++)
#pragma unroll
        for (int j = 0; j < 4; j++) o[np][j] *= alo[j];
#pragma unroll
      for (int j = 0; j < 4; j++) ls[j] *= alo[j];
    }
    float nm = -mr;
#pragma unroll
    for (int mk = 0; mk < 4; mk++)
#pragma unroll
      for (int j = 0; j < 4; j++)
        st[mk][j] = exp2f(fmaf(st[mk][j], sc2, nm));

    // P -> LDS (per-wave, stride 72), then read back as PV A-frags
#pragma unroll
    for (int mk = 0; mk < 4; mk++) {
      ushort4 pw;
      pw.x = f2bfh(st[mk][0]); pw.y = f2bfh(st[mk][1]);
      pw.z = f2bfh(st[mk][2]); pw.w = f2bfh(st[mk][3]);
      *(ushort4*)&Ps[wid][row16 * 72 + mk * 16 + kq * 4] = pw;
    }
    bf16x8 pf[2];
#pragma unroll
    for (int k2 = 0; k2 < 2; k2++)
      pf[k2] = *(const bf16x8*)&Ps[wid][row16 * 72 + k2 * 32 + kq * 8];

    // V(t) ready? (outstanding: V(t):2 then K(t+1):2 -> wait to 2 = V done)
    asm volatile("s_waitcnt vmcnt(2)" ::: "memory");
    __builtin_amdgcn_s_barrier();

    // ---- O += P V ; l += P . 1 ----
#pragma unroll
    for (int np = 0; np < 8; np++) {
      int vrow = np * 16 + row16;
      bf16x8 bv0 = *(const bf16x8*)&Vs[vrow * 64 + ((kq ^ r3) * 8)];
      bf16x8 bv1 = *(const bf16x8*)&Vs[vrow * 64 + (((4 + kq) ^ r3) * 8)];
      __builtin_amdgcn_s_setprio(1);
      o[np] = MFMA16(pf[0], bv0, o[np]);
      o[np] = MFMA16(pf[1], bv1, o[np]);
      __builtin_amdgcn_s_setprio(0);
    }
    ls = MFMA16(pf[0], ones, ls);
    ls = MFMA16(pf[1], ones, ls);

    __builtin_amdgcn_s_barrier();   // all waves done reading Vs
    stageV(tn);                     // prefetch next V (consumed after next QK+softmax)
    asm volatile("s_waitcnt vmcnt(2)" ::: "memory");  // K(t+1) done (V(t+1) in flight)
    __builtin_amdgcn_s_barrier();
  }
  asm volatile("s_waitcnt vmcnt(0)" ::: "memory");    // drain dangling prefetches

  // epilogue: ls already in O layout (row = kq*4+j)
#pragma unroll
  for (int j = 0; j < 4; j++) {
    float inv = 1.f / ls[j];
    size_t orow = prow + (size_t)qt * 128 + wid * 16 + kq * 4 + j;
#pragma unroll
    for (int np = 0; np < 8; np++)
      Y[orow * 2048 + h * 128 + np * 16 + row16] = f2bfh(o[np][j] * inv);
  }
}

extern "C" void kernel_launch(void* const* d_in, const int* in_sizes, int n_in,
                              void* d_out, int out_size, void* d_ws, size_t ws_size,
                              hipStream_t stream) {
  const float* x     = (const float*)d_in[0];
  const float* in_w  = (const float*)d_in[1];
  const float* in_b  = (const float*)d_in[2];
  const float* out_w = (const float*)d_in[3];
  const float* out_b = (const float*)d_in[4];
  float* out = (float*)d_out;

  unsigned short* xb     = (unsigned short*)d_ws;            // 8388608
  unsigned short* wb     = xb + 8388608;                     // 6291456
  unsigned short* owb    = wb + 6291456;                     // 4194304
  unsigned short* packed = owb + 4194304;                    // 12582912
  unsigned short* vt     = packed + 12582912;                // 2097152
  unsigned short* y      = vt + 2097152;                     // 8388608

  k_cvt3<<<dim3(2048), dim3(256), 0, stream>>>(x, xb, 8388608 / 4,
                                               in_w, wb, 6291456 / 4,
                                               out_w, owb, 4194304 / 4);

  k_gemm<true><<<dim3(24, 32), dim3(256), 0, stream>>>(xb, wb, in_b, packed, 4096, 3072, 2048);
  k_vt<<<dim3(32, 8), dim3(256), 0, stream>>>(packed, vt);
  k_flash<<<dim3(512), dim3(512), 0, stream>>>(packed, vt, y);
  k_gemm<false><<<dim3(16, 32), dim3(256), 0, stream>>>(y, owb, out_b, out, 4096, 2048, 2048);
}

// Round 7
// 225.212 us; speedup vs baseline: 1.4740x; 1.0050x over previous
//
#include <hip/hip_runtime.h>
#include <hip/hip_bf16.h>
#include <stdint.h>

#define DEV __device__ __forceinline__

typedef __attribute__((ext_vector_type(8))) short bf16x8;
typedef __attribute__((ext_vector_type(4))) float f32x4;
typedef __attribute__((ext_vector_type(16))) float f32x16;

DEV unsigned short f2bf(float f) {
  unsigned u = __builtin_bit_cast(unsigned, f);
  unsigned r = u + 0x7FFF + ((u >> 16) & 1);   // RNE
  return (unsigned short)(r >> 16);
}

// native bf16 convert (compiler packs pairs into v_cvt_pk_bf16_f32)
DEV unsigned short f2bfh(float f) {
  __bf16 h = (__bf16)f;
  return __builtin_bit_cast(unsigned short, h);
}

typedef __attribute__((address_space(1))) void gvoid;
typedef __attribute__((address_space(3))) void lvoid;

DEV void g2l16(const void* g, void* l) {
  __builtin_amdgcn_global_load_lds((gvoid*)g, (lvoid*)l, 16, 0, 0);
}

#define MFMA16(a, b, c) __builtin_amdgcn_mfma_f32_16x16x32_bf16(a, b, c, 0, 0, 0)
#define MFMA32(a, b, c) __builtin_amdgcn_mfma_f32_32x32x16_bf16(a, b, c, 0, 0, 0)

// ---------------- fp32 -> bf16 convert, 3 arrays fused ----------------
__global__ void k_cvt3(const float* __restrict__ x, unsigned short* __restrict__ xo, int nx4,
                       const float* __restrict__ w, unsigned short* __restrict__ wo, int nw4,
                       const float* __restrict__ v, unsigned short* __restrict__ vo, int nv4) {
  int i = blockIdx.x * blockDim.x + threadIdx.x;
  int stride = gridDim.x * blockDim.x;
  int tot = nx4 + nw4 + nv4;
  for (; i < tot; i += stride) {
    const float* src; unsigned short* dst; int j = i;
    if (j < nx4) { src = x; dst = xo; }
    else if ((j -= nx4) < nw4) { src = w; dst = wo; }
    else { j -= nw4; src = v; dst = vo; }
    float4 val = reinterpret_cast<const float4*>(src)[j];
    ushort4 o;
    o.x = f2bf(val.x); o.y = f2bf(val.y); o.z = f2bf(val.z); o.w = f2bf(val.w);
    reinterpret_cast<ushort4*>(dst)[j] = o;
  }
}

// ---------------- 128x128 tile bf16 GEMM, B given as B^T [N][K], +bias ----------------
template<bool BF16OUT>
__global__ __launch_bounds__(256, 2) void k_gemm(
    const unsigned short* __restrict__ A, const unsigned short* __restrict__ B,
    const float* __restrict__ bias, void* __restrict__ C,
    int M, int N, int K) {
  __shared__ unsigned short As[128 * 32];
  __shared__ unsigned short Bs[128 * 32];
  int tid = threadIdx.x;
  int lane = tid & 63, wid = tid >> 6;
  int bm = blockIdx.y * 128, bn = blockIdx.x * 128;
  int wm = (wid >> 1) * 64, wn = (wid & 1) * 64;
  int row16 = lane & 15, kq = lane >> 4;
  f32x4 acc[4][4] = {};
  int r = tid >> 2, c = (tid & 3) * 8;
  const unsigned short* Ag = A + (size_t)(bm + r) * K + c;
  const unsigned short* Bg = B + (size_t)(bn + r) * K + c;
  for (int k0 = 0; k0 < K; k0 += 32) {
    g2l16(Ag + k0, &As[tid * 8]);
    g2l16(Ag + (size_t)64 * K + k0, &As[2048 + tid * 8]);
    g2l16(Bg + k0, &Bs[tid * 8]);
    g2l16(Bg + (size_t)64 * K + k0, &Bs[2048 + tid * 8]);
    __syncthreads();
    bf16x8 a[4], b[4];
#pragma unroll
    for (int m = 0; m < 4; m++) a[m] = *(const bf16x8*)&As[(wm + m * 16 + row16) * 32 + kq * 8];
#pragma unroll
    for (int n = 0; n < 4; n++) b[n] = *(const bf16x8*)&Bs[(wn + n * 16 + row16) * 32 + kq * 8];
    __builtin_amdgcn_s_setprio(1);
#pragma unroll
    for (int m = 0; m < 4; m++)
#pragma unroll
      for (int n = 0; n < 4; n++)
        acc[m][n] = MFMA16(a[m], b[n], acc[m][n]);
    __builtin_amdgcn_s_setprio(0);
    __syncthreads();
  }
#pragma unroll
  for (int n = 0; n < 4; n++) {
    int col = bn + wn + n * 16 + row16;
    float bv = bias[col];
#pragma unroll
    for (int m = 0; m < 4; m++) {
      int rw = bm + wm + m * 16 + kq * 4;
#pragma unroll
      for (int j = 0; j < 4; j++) {
        float v = acc[m][n][j] + bv;
        if (BF16OUT) ((unsigned short*)C)[(size_t)(rw + j) * N + col] = f2bf(v);
        else         ((float*)C)[(size_t)(rw + j) * N + col] = v;
      }
    }
  }
}

// ---------------- V transpose: packed[b,t,2560+kv*128+d] -> vT[(b*4+kv)*128+d][t] ----------------
__global__ void k_vt(const unsigned short* __restrict__ packed, unsigned short* __restrict__ vT) {
  __shared__ unsigned short tile[64][136];
  int g = blockIdx.y;            // b*4+kv
  int b = g >> 2, kv = g & 3;
  int t0 = blockIdx.x * 64;
  int tid = threadIdx.x;
#pragma unroll
  for (int i = 0; i < 4; i++) {
    int tl = i * 16 + (tid >> 4);
    int d0 = (tid & 15) * 8;
    bf16x8 v = *(const bf16x8*)&packed[(size_t)(b * 2048 + t0 + tl) * 3072 + 2560 + kv * 128 + d0];
    *(bf16x8*)&tile[tl][d0] = v;
  }
  __syncthreads();
  int d = tid >> 1, ts = (tid & 1) * 32;
  size_t obase = (size_t)(g * 128 + d) * 2048 + t0 + ts;
#pragma unroll
  for (int j = 0; j < 4; j++) {
    bf16x8 o;
#pragma unroll
    for (int e = 0; e < 8; e++) o[e] = (short)tile[ts + j * 8 + e][d];
    *(bf16x8*)&vT[obase + j * 8] = o;
  }
}

// ---------------- flash attention, 32x32 MFMA, pipelined ----------------
// grid: 512 1-D blocks; decode: (b,kv) = id&7 (XCD-affine), then h-low, q-tile.
// block 256 = 4 waves; each wave owns 32 q-rows (QBLK=128). Swapped QK^T
// (S^T = mfma(K,Q), 32x32x16) so q = lane&31 lane-local: softmax reduce =
// in-lane fold + 1 shfl_xor(32). Per-wave LDS read per tile = exactly one
// K-tile + one V-tile (reuse doubled vs 16x16). All LDS tiles slot-XOR
// swizzled to the b128 bank floor. K dbuf, V single, counted vmcnt(4).
__global__ __launch_bounds__(256, 2) void k_flash(
    const unsigned short* __restrict__ packed,
    const unsigned short* __restrict__ vT,
    unsigned short* __restrict__ Y) {
  __shared__ unsigned short Ks[2][64 * 128];   // 32KB; Q[128][128] staging spans both
  __shared__ unsigned short Vs[128 * 64];      // 16KB  (V^T: row=d, col=kv)
  __shared__ unsigned short Ps[4][32 * 64];    // 16KB per-wave P, slot-XOR swizzled
  __shared__ float Axc[4][32];
  int tid = threadIdx.x, lane = tid & 63, wid = tid >> 6;
  int l31 = lane & 31, hi = lane >> 5;
  int kx = l31 & 15;                           // K/Q swizzle key (16 slots/row)
  int vx = l31 & 7;                            // V/P swizzle key (8 slots/row)
  int g = blockIdx.x;
  int s8 = g & 7;                              // XCD-affine (b,kv)
  int b = s8 >> 2, kv = s8 & 3;
  int w = g >> 3;
  int h = kv * 4 + (w & 3);
  int qt = w >> 2;                             // 16 q-tiles x 128 rows
  size_t prow = (size_t)b * 2048;

  unsigned short* Q = &Ks[0][0];
  {  // stage Q [128 q][128 d] swizzled (8 passes x 16 rows)
    int rr = tid >> 4;
    int cc = ((tid & 15) ^ rr) * 8;
    const unsigned short* qg = packed + (prow + qt * 128 + rr) * 3072 + h * 128 + cc;
#pragma unroll
    for (int i = 0; i < 8; i++)
      g2l16(qg + (size_t)i * 16 * 3072, &Q[i * 2048 + tid * 8]);
  }
  asm volatile("s_waitcnt vmcnt(0)" ::: "memory");
  __builtin_amdgcn_s_barrier();
  bf16x8 q[8];
  int qrow = wid * 32 + l31;
#pragma unroll
  for (int kc = 0; kc < 8; kc++)
    q[kc] = *(const bf16x8*)&Q[qrow * 128 + (((2 * kc + hi) ^ kx) * 8)];
  asm volatile("s_waitcnt lgkmcnt(0)" ::: "memory");
  __builtin_amdgcn_sched_barrier(0);
  __builtin_amdgcn_s_barrier();   // Q consumed; Ks region reusable

  const unsigned short* kg0 = packed + prow * 3072 + 2048 + kv * 128;
  const unsigned short* vg0 = vT + (size_t)(b * 4 + kv) * 128 * 2048;
  int krr = tid >> 4;                           // 0..15
  int kcc = ((tid & 15) ^ krr) * 8;
  int vrr = tid >> 3;                           // 0..31
  int vcc = ((tid & 7) ^ (vrr & 7)) * 8;

  auto stageK = [&](int t, int kbuf) {          // 4 passes x 16 rows
    const unsigned short* kg = kg0 + (size_t)(t * 64 + krr) * 3072 + kcc;
#pragma unroll
    for (int i = 0; i < 4; i++)
      g2l16(kg + (size_t)i * 16 * 3072, &Ks[kbuf][i * 2048 + tid * 8]);
  };
  auto stageV = [&](int t) {                    // 4 passes x 32 rows (of 128 d-rows)
    const unsigned short* vg = vg0 + (size_t)vrr * 2048 + t * 64 + vcc;
#pragma unroll
    for (int i = 0; i < 4; i++)
      g2l16(vg + (size_t)i * 32 * 2048, &Vs[i * 2048 + tid * 8]);
  };

  stageK(0, 0);
  stageV(0);
  asm volatile("s_waitcnt vmcnt(4)" ::: "memory");   // K(0) done (V(0) in flight)
  __builtin_amdgcn_s_barrier();

  f32x16 o[4] = {};
  float mr = -1e30f, lr = 0.f;
  const float sc2 = 0.08838834764831845f * 1.4426950408889634f;  // scale*log2e

  for (int t = 0; t < 32; t++) {
    int kb = t & 1;
    int tn = t < 31 ? t + 1 : 31;   // clamp keeps vmcnt counts uniform

    // ---- QK^T: S^T[kv][q] = K Q^T, two 32-kv blocks ----
    f32x16 st[2] = {};
#pragma unroll
    for (int kb2 = 0; kb2 < 2; kb2++) {
      bf16x8 ak[8];
#pragma unroll
      for (int kc = 0; kc < 8; kc++)
        ak[kc] = *(const bf16x8*)&Ks[kb][(kb2 * 32 + l31) * 128 + (((2 * kc + hi) ^ kx) * 8)];
      __builtin_amdgcn_s_setprio(1);
#pragma unroll
      for (int kc = 0; kc < 8; kc++)
        st[kb2] = MFMA32(ak[kc], q[kc], st[kb2]);
      __builtin_amdgcn_s_setprio(0);
    }

    // prefetch next K tile into the other buffer (waited at end of iter)
    stageK(tn, kb ^ 1);

    // ---- online softmax (log2 domain), q lane-local across 32 lanes ----
    float m0 = -1e30f, m1 = -1e30f;
#pragma unroll
    for (int r = 0; r < 16; r += 2) {
      m0 = fmaxf(m0, fmaxf(st[0][r], st[0][r + 1]));
      m1 = fmaxf(m1, fmaxf(st[1][r], st[1][r + 1]));
    }
    float p = fmaxf(m0, m1);
    p = fmaxf(p, __shfl_xor(p, 32));
    p *= sc2;                     // scaled-log2 domain
    if (!__all(p <= mr + 8.f)) {  // defer-max: rescale only on real growth
      float mn = fmaxf(mr, p);
      float al = exp2f(mr - mn);
      mr = mn;
      lr *= al;
      Axc[wid][l31] = al;         // both hi-halves write identical value
      float alo[16];
#pragma unroll
      for (int r = 0; r < 16; r++)
        alo[r] = Axc[wid][(r & 3) + 8 * (r >> 2) + 4 * hi];
#pragma unroll
      for (int db = 0; db < 4; db++)
#pragma unroll
        for (int r = 0; r < 16; r++) o[db][r] *= alo[r];
    }
    float nm = -mr;
    float rs = 0.f;
#pragma unroll
    for (int kb2 = 0; kb2 < 2; kb2++) {
      float s[4];
#pragma unroll
      for (int u = 0; u < 4; u++) {
        st[kb2][4 * u + 0] = exp2f(fmaf(st[kb2][4 * u + 0], sc2, nm));
        st[kb2][4 * u + 1] = exp2f(fmaf(st[kb2][4 * u + 1], sc2, nm));
        st[kb2][4 * u + 2] = exp2f(fmaf(st[kb2][4 * u + 2], sc2, nm));
        st[kb2][4 * u + 3] = exp2f(fmaf(st[kb2][4 * u + 3], sc2, nm));
        s[u] = (st[kb2][4 * u + 0] + st[kb2][4 * u + 1]) +
               (st[kb2][4 * u + 2] + st[kb2][4 * u + 3]);
      }
      rs += (s[0] + s[1]) + (s[2] + s[3]);
    }
    rs += __shfl_xor(rs, 32);
    lr += rs;

    // P -> LDS (per-wave [32 q][64 kv], 16B-slot XOR q&7), read back as A-frags
#pragma unroll
    for (int kb2 = 0; kb2 < 2; kb2++)
#pragma unroll
      for (int u = 0; u < 4; u++) {
        ushort4 pw;
        pw.x = f2bfh(st[kb2][4 * u + 0]);
        pw.y = f2bfh(st[kb2][4 * u + 1]);
        pw.z = f2bfh(st[kb2][4 * u + 2]);
        pw.w = f2bfh(st[kb2][4 * u + 3]);
        *(ushort4*)&Ps[wid][l31 * 64 + (((u + 4 * kb2) ^ vx) * 8) + hi * 4] = pw;
      }
    bf16x8 pf[4];
#pragma unroll
    for (int ks = 0; ks < 4; ks++)
      pf[ks] = *(const bf16x8*)&Ps[wid][l31 * 64 + (((2 * ks + hi) ^ vx) * 8)];

    // V(t) ready? (outstanding: V(t):4 then K(t+1):4 -> wait to 4 = V done)
    asm volatile("s_waitcnt vmcnt(4)" ::: "memory");
    __builtin_amdgcn_s_barrier();

    // ---- O += P V ----
#pragma unroll
    for (int db = 0; db < 4; db++) {
      bf16x8 bv[4];
#pragma unroll
      for (int ks = 0; ks < 4; ks++)
        bv[ks] = *(const bf16x8*)&Vs[(32 * db + l31) * 64 + (((2 * ks + hi) ^ vx) * 8)];
      __builtin_amdgcn_s_setprio(1);
#pragma unroll
      for (int ks = 0; ks < 4; ks++)
        o[db] = MFMA32(pf[ks], bv[ks], o[db]);
      __builtin_amdgcn_s_setprio(0);
    }

    __builtin_amdgcn_s_barrier();   // all waves done reading Vs
    stageV(tn);                     // prefetch next V (consumed after next QK+softmax)
    asm volatile("s_waitcnt vmcnt(4)" ::: "memory");  // K(t+1) done (V(t+1) in flight)
    __builtin_amdgcn_s_barrier();
  }
  asm volatile("s_waitcnt vmcnt(0)" ::: "memory");    // drain dangling prefetches

  // epilogue: redistribute l (softmax layout q=l31 -> O layout q=(r&3)+8*(r>>2)+4hi)
  Axc[wid][l31] = lr;
#pragma unroll
  for (int r = 0; r < 16; r++) {
    int ql = (r & 3) + 8 * (r >> 2) + 4 * hi;
    float inv = 1.f / Axc[wid][ql];
    size_t orow = prow + (size_t)qt * 128 + wid * 32 + ql;
#pragma unroll
    for (int db = 0; db < 4; db++)
      Y[orow * 2048 + h * 128 + db * 32 + l31] = f2bfh(o[db][r] * inv);
  }
}

extern "C" void kernel_launch(void* const* d_in, const int* in_sizes, int n_in,
                              void* d_out, int out_size, void* d_ws, size_t ws_size,
                              hipStream_t stream) {
  const float* x     = (const float*)d_in[0];
  const float* in_w  = (const float*)d_in[1];
  const float* in_b  = (const float*)d_in[2];
  const float* out_w = (const float*)d_in[3];
  const float* out_b = (const float*)d_in[4];
  float* out = (float*)d_out;

  unsigned short* xb     = (unsigned short*)d_ws;            // 8388608
  unsigned short* wb     = xb + 8388608;                     // 6291456
  unsigned short* owb    = wb + 6291456;                     // 4194304
  unsigned short* packed = owb + 4194304;                    // 12582912
  unsigned short* vt     = packed + 12582912;                // 2097152
  unsigned short* y      = vt + 2097152;                     // 8388608

  k_cvt3<<<dim3(2048), dim3(256), 0, stream>>>(x, xb, 8388608 / 4,
                                               in_w, wb, 6291456 / 4,
                                               out_w, owb, 4194304 / 4);

  k_gemm<true><<<dim3(24, 32), dim3(256), 0, stream>>>(xb, wb, in_b, packed, 4096, 3072, 2048);
  k_vt<<<dim3(32, 8), dim3(256), 0, stream>>>(packed, vt);
  k_flash<<<dim3(512), dim3(256), 0, stream>>>(packed, vt, y);
  k_gemm<false><<<dim3(16, 32), dim3(256), 0, stream>>>(y, owb, out_b, out, 4096, 2048, 2048);
}